// Round 3
// baseline (501.038 us; speedup 1.0000x reference)
//
#include <hip/hip_runtime.h>
#include <math.h>

#define BN_EPS 1e-5f

typedef short short8 __attribute__((ext_vector_type(8)));
typedef float floatx4 __attribute__((ext_vector_type(4)));

#define MFMA16(a, b, c) __builtin_amdgcn_mfma_f32_16x16x32_bf16((a), (b), (c), 0, 0, 0)

// fp32 -> bf16 bits, round-to-nearest-even
__device__ __forceinline__ unsigned short f2bf(float x) {
    unsigned u = __float_as_uint(x);
    u = u + 0x7fffu + ((u >> 16) & 1u);
    return (unsigned short)(u >> 16);
}
__device__ __forceinline__ float bf2f(unsigned short b) {
    return __uint_as_float(((unsigned)b) << 16);
}

// ---------------------------------------------------------------------------
// CSR build, pass 1: degree histogram (reads dst half only)
// ---------------------------------------------------------------------------
__global__ void hist_kernel(const int* __restrict__ ei, int* __restrict__ deg, int E) {
    int e = blockIdx.x * 256 + threadIdx.x;
    if (e >= E) return;
    atomicAdd(&deg[ei[E + e]], 1);
}

// ---------------------------------------------------------------------------
// CSR build, pass 2: single-block exclusive scan over deg -> offs, cursor
// ---------------------------------------------------------------------------
__global__ __launch_bounds__(1024)
void scan_kernel(const int* __restrict__ deg, int* __restrict__ offs,
                 int* __restrict__ cursor, int n) {
    __shared__ int sums[1024];
    int t = threadIdx.x;
    int chunk = (n + 1023) / 1024;
    int lo = t * chunk;
    int hi = lo + chunk; if (hi > n) hi = n; if (lo > n) lo = n;
    int s = 0;
    for (int i = lo; i < hi; ++i) s += deg[i];
    sums[t] = s;
    __syncthreads();
    for (int d = 1; d < 1024; d <<= 1) {
        int v = (t >= d) ? sums[t - d] : 0;
        __syncthreads();
        sums[t] += v;
        __syncthreads();
    }
    int run = (t == 0) ? 0 : sums[t - 1];
    for (int i = lo; i < hi; ++i) {
        offs[i] = run;
        cursor[i] = run;
        run += deg[i];
    }
}

// ---------------------------------------------------------------------------
// CSR build, pass 3: scatter srcs into compact adj (L2-resident, ~3.2 MB)
// ---------------------------------------------------------------------------
__global__ void scatter_kernel(const int* __restrict__ ei, int* __restrict__ cursor,
                               int* __restrict__ adj, int E) {
    int e = blockIdx.x * 256 + threadIdx.x;
    if (e >= E) return;
    int s = ei[e];
    int d = ei[E + e];
    int pos = atomicAdd(&cursor[d], 1);
    adj[pos] = s;
}

// ---------------------------------------------------------------------------
// Pack BN-folded weights into MFMA B-fragment order, split bf16 hi/lo.
// Blocks 0..2: GIN layers. Block 3: head (lin1+bn folded, lin2 zero-padded).
// frag value: B[k = kk*32 + (lane>>4)*8 + j][n = ct*16 + (lane&15)]
// ---------------------------------------------------------------------------
__global__ void pack_kernel(const float* __restrict__ W1, const float* __restrict__ b1,
                            const float* __restrict__ g1, const float* __restrict__ bt1,
                            const float* __restrict__ m1, const float* __restrict__ v1,
                            const float* __restrict__ W2, const float* __restrict__ b2,
                            const float* __restrict__ gc, const float* __restrict__ bc,
                            const float* __restrict__ mc, const float* __restrict__ vc,
                            const float* __restrict__ l1W, const float* __restrict__ l1b,
                            const float* __restrict__ gbn, const float* __restrict__ bbn,
                            const float* __restrict__ mbn, const float* __restrict__ vbn,
                            const float* __restrict__ l2W, const float* __restrict__ l2b,
                            unsigned short* __restrict__ w1p, unsigned short* __restrict__ w2p,
                            float* __restrict__ bias1, float* __restrict__ bias2,
                            unsigned short* __restrict__ w1ph, unsigned short* __restrict__ w2ph,
                            float* __restrict__ bias1h, float* __restrict__ bias2h) {
    int l = blockIdx.x, t = threadIdx.x;
    if (l < 3) {
        const float* W1l = W1 + (size_t)l * 64 * 128;
        const float* W2l = W2 + (size_t)l * 128 * 64;
        if (t < 128) {
            float s = g1[l * 128 + t] * rsqrtf(v1[l * 128 + t] + BN_EPS);
            bias1[l * 128 + t] = (b1[l * 128 + t] - m1[l * 128 + t]) * s + bt1[l * 128 + t];
        }
        if (t < 64) {
            float s = gc[l * 64 + t] * rsqrtf(vc[l * 64 + t] + BN_EPS);
            bias2[l * 64 + t] = (b2[l * 64 + t] - mc[l * 64 + t]) * s + bc[l * 64 + t];
        }
        for (int idx = t; idx < 16384; idx += 256) {
            int j = idx & 7, lane = (idx >> 3) & 63, hl = (idx >> 9) & 1;
            int kk = (idx >> 10) & 1, ct = idx >> 11;
            int k = kk * 32 + (lane >> 4) * 8 + j;
            int nn = ct * 16 + (lane & 15);
            float s = g1[l * 128 + nn] * rsqrtf(v1[l * 128 + nn] + BN_EPS);
            float w = W1l[k * 128 + nn] * s;
            unsigned short hi = f2bf(w);
            w1p[(size_t)l * 16384 + idx] = hl ? f2bf(w - bf2f(hi)) : hi;
        }
        for (int idx = t; idx < 16384; idx += 256) {
            int j = idx & 7, lane = (idx >> 3) & 63, hl = (idx >> 9) & 1;
            int kk = (idx >> 10) & 3, ct = idx >> 12;
            int k = kk * 32 + (lane >> 4) * 8 + j;
            int nn = ct * 16 + (lane & 15);
            float s = gc[l * 64 + nn] * rsqrtf(vc[l * 64 + nn] + BN_EPS);
            float w = W2l[k * 64 + nn] * s;
            unsigned short hi = f2bf(w);
            w2p[(size_t)l * 16384 + idx] = hl ? f2bf(w - bf2f(hi)) : hi;
        }
    } else {
        // head: lin1 (64x64, BN-folded) and lin2 (64x40 zero-padded to 64)
        if (t < 64) {
            float s = gbn[t] * rsqrtf(vbn[t] + BN_EPS);
            bias1h[t] = (l1b[t] - mbn[t]) * s + bbn[t];
            bias2h[t] = (t < 40) ? l2b[t] : 0.0f;
        }
        for (int idx = t; idx < 8192; idx += 256) {
            int j = idx & 7, lane = (idx >> 3) & 63, hl = (idx >> 9) & 1;
            int kk = (idx >> 10) & 1, ct = idx >> 11;   // ct<4
            int k = kk * 32 + (lane >> 4) * 8 + j;
            int nn = ct * 16 + (lane & 15);
            float s = gbn[nn] * rsqrtf(vbn[nn] + BN_EPS);
            float w = l1W[k * 64 + nn] * s;
            unsigned short hi = f2bf(w);
            w1ph[idx] = hl ? f2bf(w - bf2f(hi)) : hi;
        }
        for (int idx = t; idx < 8192; idx += 256) {
            int j = idx & 7, lane = (idx >> 3) & 63, hl = (idx >> 9) & 1;
            int kk = (idx >> 10) & 1, ct = idx >> 11;
            int k = kk * 32 + (lane >> 4) * 8 + j;
            int nn = ct * 16 + (lane & 15);
            float w = (nn < 40) ? l2W[k * 40 + nn] : 0.0f;
            unsigned short hi = f2bf(w);
            w2ph[idx] = hl ? f2bf(w - bf2f(hi)) : hi;
        }
    }
}

// ---------------------------------------------------------------------------
// h[i] = x[i] + sum_{j in N(i)} x[j]; one wave per node; CSR neighbor list;
// 4 independent load chains; emits bf16 hi/lo split for the MFMA A-operand.
// ---------------------------------------------------------------------------
__global__ void gather_kernel(const float* __restrict__ x, const int* __restrict__ adj,
                              const int* __restrict__ offs, const int* __restrict__ deg,
                              unsigned short* __restrict__ hhi,
                              unsigned short* __restrict__ hlo, int n) {
    int gid = blockIdx.x * blockDim.x + threadIdx.x;
    int node = gid >> 6;
    if (node >= n) return;
    int lane = threadIdx.x & 63;
    int d = deg[node];
    int off = offs[node];
    float acc = x[(size_t)node * 64 + lane];        // self term (GIN eps=0)
    float a1 = 0.f, a2 = 0.f, a3 = 0.f;
    for (int base = 0; base < d; base += 64) {
        int m = d - base; if (m > 64) m = 64;
        int myslot = (lane < m) ? adj[off + base + lane] : 0;
        int c = 0;
        for (; c + 4 <= m; c += 4) {
            int s0 = __shfl(myslot, c, 64);
            int s1 = __shfl(myslot, c + 1, 64);
            int s2 = __shfl(myslot, c + 2, 64);
            int s3 = __shfl(myslot, c + 3, 64);
            acc += x[(size_t)s0 * 64 + lane];
            a1  += x[(size_t)s1 * 64 + lane];
            a2  += x[(size_t)s2 * 64 + lane];
            a3  += x[(size_t)s3 * 64 + lane];
        }
        for (; c < m; ++c) {
            int s = __shfl(myslot, c, 64);
            acc += x[(size_t)s * 64 + lane];
        }
    }
    acc += (a1 + a2) + a3;
    unsigned short hi = f2bf(acc);
    unsigned short lo = f2bf(acc - bf2f(hi));
    hhi[(size_t)node * 64 + lane] = hi;
    hlo[(size_t)node * 64 + lane] = lo;
}

// ---------------------------------------------------------------------------
// MFMA GIN MLP, split-bf16 (hi+lo, 3 products) == fp32-accurate.
// Block = 4 waves, one 16-node tile. Wave w owns stage-A col-tiles {2w,2w+1}
// and stage-B col-tile w. Weights live in registers (pre-packed frags).
// ---------------------------------------------------------------------------
__global__ __launch_bounds__(256)
void mlp_mfma(const unsigned short* __restrict__ hhi, const unsigned short* __restrict__ hlo,
              const unsigned short* __restrict__ w1p, const unsigned short* __restrict__ w2p,
              const float* __restrict__ bias1, const float* __restrict__ bias2,
              float* __restrict__ xout, int n) {
    __shared__ __attribute__((aligned(16))) unsigned short h2hi[16 * 136];
    __shared__ __attribute__((aligned(16))) unsigned short h2lo[16 * 136];

    const int t = threadIdx.x;
    const int wv = t >> 6, lane = t & 63;
    const int quad = lane >> 4, l16 = lane & 15;

    short8 w1f[2][2][2];   // [ct_local][kk][hi/lo]
#pragma unroll
    for (int c = 0; c < 2; ++c)
#pragma unroll
        for (int kk = 0; kk < 2; ++kk)
#pragma unroll
            for (int hl = 0; hl < 2; ++hl) {
                int ct = wv * 2 + c;
                w1f[c][kk][hl] = *(const short8*)&w1p[(size_t)(((ct * 2 + kk) * 2 + hl) * 64 + lane) * 8];
            }
    short8 w2f[4][2];      // [kk][hi/lo], ct = wv
#pragma unroll
    for (int kk = 0; kk < 4; ++kk)
#pragma unroll
        for (int hl = 0; hl < 2; ++hl)
            w2f[kk][hl] = *(const short8*)&w2p[(size_t)(((wv * 4 + kk) * 2 + hl) * 64 + lane) * 8];

    float b1v0 = bias1[(wv * 2 + 0) * 16 + l16];
    float b1v1 = bias1[(wv * 2 + 1) * 16 + l16];
    float b2v  = bias2[wv * 16 + l16];

    const int tile = blockIdx.x * 16;
    int arow = tile + l16;
    if (arow >= n) arow = n - 1;

    const unsigned short* hr = hhi + (size_t)arow * 64 + quad * 8;
    const unsigned short* lr = hlo + (size_t)arow * 64 + quad * 8;
    short8 ah0 = *(const short8*)hr;
    short8 ah1 = *(const short8*)(hr + 32);
    short8 al0 = *(const short8*)lr;
    short8 al1 = *(const short8*)(lr + 32);

    floatx4 accA0 = {0.f, 0.f, 0.f, 0.f};
    floatx4 accA1 = {0.f, 0.f, 0.f, 0.f};
    accA0 = MFMA16(ah0, w1f[0][0][0], accA0);
    accA0 = MFMA16(ah0, w1f[0][0][1], accA0);
    accA0 = MFMA16(al0, w1f[0][0][0], accA0);
    accA0 = MFMA16(ah1, w1f[0][1][0], accA0);
    accA0 = MFMA16(ah1, w1f[0][1][1], accA0);
    accA0 = MFMA16(al1, w1f[0][1][0], accA0);
    accA1 = MFMA16(ah0, w1f[1][0][0], accA1);
    accA1 = MFMA16(ah0, w1f[1][0][1], accA1);
    accA1 = MFMA16(al0, w1f[1][0][0], accA1);
    accA1 = MFMA16(ah1, w1f[1][1][0], accA1);
    accA1 = MFMA16(ah1, w1f[1][1][1], accA1);
    accA1 = MFMA16(al1, w1f[1][1][0], accA1);

#pragma unroll
    for (int r = 0; r < 4; ++r) {
        int node = quad * 4 + r;
        {
            float v = fmaxf(accA0[r] + b1v0, 0.f);
            unsigned short hi = f2bf(v);
            int col = (wv * 2 + 0) * 16 + l16;
            h2hi[node * 136 + col] = hi;
            h2lo[node * 136 + col] = f2bf(v - bf2f(hi));
        }
        {
            float v = fmaxf(accA1[r] + b1v1, 0.f);
            unsigned short hi = f2bf(v);
            int col = (wv * 2 + 1) * 16 + l16;
            h2hi[node * 136 + col] = hi;
            h2lo[node * 136 + col] = f2bf(v - bf2f(hi));
        }
    }
    __syncthreads();

    floatx4 accB = {0.f, 0.f, 0.f, 0.f};
#pragma unroll
    for (int kk = 0; kk < 4; ++kk) {
        short8 a2h = *(const short8*)&h2hi[l16 * 136 + kk * 32 + quad * 8];
        short8 a2l = *(const short8*)&h2lo[l16 * 136 + kk * 32 + quad * 8];
        accB = MFMA16(a2h, w2f[kk][0], accB);
        accB = MFMA16(a2h, w2f[kk][1], accB);
        accB = MFMA16(a2l, w2f[kk][0], accB);
    }
    int col2 = wv * 16 + l16;
#pragma unroll
    for (int r = 0; r < 4; ++r) {
        int node = tile + quad * 4 + r;
        if (node < n)
            xout[(size_t)node * 64 + col2] = fmaxf(accB[r] + b2v, 0.f);
    }
}

// ---------------------------------------------------------------------------
// MFMA head: relu(bn1(x@lin1+b)) @ lin2pad -> log_softmax(40).
// Block = 4 waves, one 16-node tile; wave w owns col-tile w for both stages.
// ---------------------------------------------------------------------------
__global__ __launch_bounds__(256)
void head_mfma(const float* __restrict__ xin,
               const unsigned short* __restrict__ w1ph, const unsigned short* __restrict__ w2ph,
               const float* __restrict__ bias1h, const float* __restrict__ bias2h,
               float* __restrict__ out, int n) {
    __shared__ __attribute__((aligned(16))) unsigned short h2hi[16 * 72];
    __shared__ __attribute__((aligned(16))) unsigned short h2lo[16 * 72];
    __shared__ float zbuf[16][68];

    const int t = threadIdx.x;
    const int wv = t >> 6, lane = t & 63;
    const int quad = lane >> 4, l16 = lane & 15;

    short8 w1f[2][2];  // [kk][hi/lo], ct = wv
    short8 w2f[2][2];
#pragma unroll
    for (int kk = 0; kk < 2; ++kk)
#pragma unroll
        for (int hl = 0; hl < 2; ++hl) {
            w1f[kk][hl] = *(const short8*)&w1ph[(size_t)(((wv * 2 + kk) * 2 + hl) * 64 + lane) * 8];
            w2f[kk][hl] = *(const short8*)&w2ph[(size_t)(((wv * 2 + kk) * 2 + hl) * 64 + lane) * 8];
        }
    float b1v = bias1h[wv * 16 + l16];
    float b2v = bias2h[wv * 16 + l16];

    const int tile = blockIdx.x * 16;
    int arow = tile + l16;
    if (arow >= n) arow = n - 1;

    // A-frags from fp32 input, split hi/lo
    short8 ah[2], al[2];
#pragma unroll
    for (int kk = 0; kk < 2; ++kk) {
        const float* xr = xin + (size_t)arow * 64 + kk * 32 + quad * 8;
        float4 xa = *(const float4*)xr;
        float4 xb = *(const float4*)(xr + 4);
        float v[8] = {xa.x, xa.y, xa.z, xa.w, xb.x, xb.y, xb.z, xb.w};
#pragma unroll
        for (int j = 0; j < 8; ++j) {
            unsigned short hi = f2bf(v[j]);
            ah[kk][j] = (short)hi;
            al[kk][j] = (short)f2bf(v[j] - bf2f(hi));
        }
    }

    floatx4 accA = {0.f, 0.f, 0.f, 0.f};
#pragma unroll
    for (int kk = 0; kk < 2; ++kk) {
        accA = MFMA16(ah[kk], w1f[kk][0], accA);
        accA = MFMA16(ah[kk], w1f[kk][1], accA);
        accA = MFMA16(al[kk], w1f[kk][0], accA);
    }
#pragma unroll
    for (int r = 0; r < 4; ++r) {
        int node = quad * 4 + r;
        float v = fmaxf(accA[r] + b1v, 0.f);
        unsigned short hi = f2bf(v);
        int col = wv * 16 + l16;
        h2hi[node * 72 + col] = hi;
        h2lo[node * 72 + col] = f2bf(v - bf2f(hi));
    }
    __syncthreads();

    floatx4 accB = {0.f, 0.f, 0.f, 0.f};
#pragma unroll
    for (int kk = 0; kk < 2; ++kk) {
        short8 a2h = *(const short8*)&h2hi[l16 * 72 + kk * 32 + quad * 8];
        short8 a2l = *(const short8*)&h2lo[l16 * 72 + kk * 32 + quad * 8];
        accB = MFMA16(a2h, w2f[kk][0], accB);
        accB = MFMA16(a2h, w2f[kk][1], accB);
        accB = MFMA16(a2l, w2f[kk][0], accB);
    }
#pragma unroll
    for (int r = 0; r < 4; ++r)
        zbuf[quad * 4 + r][wv * 16 + l16] = accB[r] + b2v;
    __syncthreads();

    // log-softmax: wave wv handles nodes wv*4 .. wv*4+3; lanes 0..39 = classes
#pragma unroll
    for (int r = 0; r < 4; ++r) {
        int nl = wv * 4 + r;
        float zi = (lane < 40) ? zbuf[nl][lane] : -INFINITY;
        float mx = zi;
#pragma unroll
        for (int msk = 1; msk < 64; msk <<= 1)
            mx = fmaxf(mx, __shfl_xor(mx, msk, 64));
        float e = (lane < 40) ? __expf(zi - mx) : 0.f;
        float se = e;
#pragma unroll
        for (int msk = 1; msk < 64; msk <<= 1)
            se += __shfl_xor(se, msk, 64);
        float lse = mx + __logf(se);
        int node = tile + nl;
        if (lane < 40 && node < n)
            out[(size_t)node * 40 + lane] = zi - lse;
    }
}

// ---------------------------------------------------------------------------
extern "C" void kernel_launch(void* const* d_in, const int* in_sizes, int n_in,
                              void* d_out, int out_size, void* d_ws, size_t ws_size,
                              hipStream_t stream) {
    const float* x    = (const float*)d_in[0];
    const int*   ei   = (const int*)d_in[1];
    const float* W1   = (const float*)d_in[2];
    const float* b1   = (const float*)d_in[3];
    const float* g1   = (const float*)d_in[4];
    const float* bt1  = (const float*)d_in[5];
    const float* m1   = (const float*)d_in[6];
    const float* v1   = (const float*)d_in[7];
    const float* W2   = (const float*)d_in[8];
    const float* b2   = (const float*)d_in[9];
    const float* gc   = (const float*)d_in[10];
    const float* bc   = (const float*)d_in[11];
    const float* mc   = (const float*)d_in[12];
    const float* vc   = (const float*)d_in[13];
    const float* l1W  = (const float*)d_in[14];
    const float* l1b  = (const float*)d_in[15];
    const float* gbn  = (const float*)d_in[16];
    const float* bbn  = (const float*)d_in[17];
    const float* mbn  = (const float*)d_in[18];
    const float* vbn  = (const float*)d_in[19];
    const float* l2W  = (const float*)d_in[20];
    const float* l2b  = (const float*)d_in[21];
    float* out = (float*)d_out;

    int N = in_sizes[0] / 64;
    int E = in_sizes[1] / 2;

    char* w = (char*)d_ws;
    int* deg = (int*)w;              w += ((size_t)N * 4 + 255) / 256 * 256;
    int* offs = (int*)w;             w += ((size_t)N * 4 + 255) / 256 * 256;
    int* cursor = (int*)w;           w += ((size_t)N * 4 + 255) / 256 * 256;
    int* adj = (int*)w;              w += ((size_t)E * 4 + 255) / 256 * 256;
    unsigned short* hhi = (unsigned short*)w;  w += (size_t)N * 64 * 2;
    unsigned short* hlo = (unsigned short*)w;  w += (size_t)N * 64 * 2;
    float* xb0 = (float*)w;          w += (size_t)N * 64 * 4;
    unsigned short* w1p = (unsigned short*)w;  w += 3 * 16384 * 2;
    unsigned short* w2p = (unsigned short*)w;  w += 3 * 16384 * 2;
    float* bias1 = (float*)w;        w += 3 * 128 * 4;
    float* bias2 = (float*)w;        w += 3 * 64 * 4;
    unsigned short* w1ph = (unsigned short*)w; w += 8192 * 2;
    unsigned short* w2ph = (unsigned short*)w; w += 8192 * 2;
    float* bias1h = (float*)w;       w += 64 * 4;
    float* bias2h = (float*)w;       w += 64 * 4;

    hipMemsetAsync(deg, 0, (size_t)N * 4, stream);
    hist_kernel<<<(E + 255) / 256, 256, 0, stream>>>(ei, deg, E);
    scan_kernel<<<1, 1024, 0, stream>>>(deg, offs, cursor, N);
    scatter_kernel<<<(E + 255) / 256, 256, 0, stream>>>(ei, cursor, adj, E);
    pack_kernel<<<4, 256, 0, stream>>>(W1, b1, g1, bt1, m1, v1, W2, b2, gc, bc, mc, vc,
                                       l1W, l1b, gbn, bbn, mbn, vbn, l2W, l2b,
                                       w1p, w2p, bias1, bias2, w1ph, w2ph, bias1h, bias2h);

    const float* cur = x;
    int nblk = (N + 15) / 16;
    for (int l = 0; l < 3; ++l) {
        gather_kernel<<<(N * 64 + 255) / 256, 256, 0, stream>>>(cur, adj, offs, deg, hhi, hlo, N);
        mlp_mfma<<<nblk, 256, 0, stream>>>(hhi, hlo,
                                           w1p + (size_t)l * 16384, w2p + (size_t)l * 16384,
                                           bias1 + (size_t)l * 128, bias2 + (size_t)l * 64,
                                           xb0, N);
        cur = xb0;
    }
    head_mfma<<<nblk, 256, 0, stream>>>(xb0, w1ph, w2ph, bias1h, bias2h, out, N);
}

// Round 4
// 402.861 us; speedup vs baseline: 1.2437x; 1.2437x over previous
//
#include <hip/hip_runtime.h>
#include <math.h>

#define BN_EPS 1e-5f

typedef short short8 __attribute__((ext_vector_type(8)));
typedef float floatx4 __attribute__((ext_vector_type(4)));

#define MFMA16(a, b, c) __builtin_amdgcn_mfma_f32_16x16x32_bf16((a), (b), (c), 0, 0, 0)

// fp32 -> bf16 bits, round-to-nearest-even
__device__ __forceinline__ unsigned short f2bf(float x) {
    unsigned u = __float_as_uint(x);
    u = u + 0x7fffu + ((u >> 16) & 1u);
    return (unsigned short)(u >> 16);
}
__device__ __forceinline__ float bf2f(unsigned short b) {
    return __uint_as_float(((unsigned)b) << 16);
}

// ---------------------------------------------------------------------------
// CSR build, pass 1: degree histogram (reads dst half only)
// ---------------------------------------------------------------------------
__global__ void hist_kernel(const int* __restrict__ ei, int* __restrict__ deg, int E) {
    int e = blockIdx.x * 256 + threadIdx.x;
    if (e >= E) return;
    atomicAdd(&deg[ei[E + e]], 1);
}

// ---------------------------------------------------------------------------
// CSR build, pass 2: range ALLOCATION (not a scan — node order irrelevant).
// Wave-level prefix sum over degrees + one atomicAdd per wave on a counter.
// ---------------------------------------------------------------------------
__global__ void alloc_kernel(const int* __restrict__ deg, int* __restrict__ offs,
                             int* __restrict__ cursor, int* __restrict__ counter, int n) {
    int i = blockIdx.x * 256 + threadIdx.x;
    int lane = threadIdx.x & 63;
    int d = (i < n) ? deg[i] : 0;
    int pre = d;
#pragma unroll
    for (int delta = 1; delta < 64; delta <<= 1) {
        int v = __shfl_up(pre, delta, 64);
        if (lane >= delta) pre += v;
    }
    int total = __shfl(pre, 63, 64);   // wave sum
    int excl = pre - d;                // exclusive prefix within wave
    int base = 0;
    if (lane == 0) base = atomicAdd(counter, total);
    base = __shfl(base, 0, 64);
    if (i < n) {
        offs[i] = base + excl;
        cursor[i] = base + excl;
    }
}

// ---------------------------------------------------------------------------
// CSR build, pass 3: scatter srcs into compact adj (L2/L3-resident, ~3.2 MB)
// ---------------------------------------------------------------------------
__global__ void scatter_kernel(const int* __restrict__ ei, int* __restrict__ cursor,
                               int* __restrict__ adj, int E) {
    int e = blockIdx.x * 256 + threadIdx.x;
    if (e >= E) return;
    int s = ei[e];
    int d = ei[E + e];
    int pos = atomicAdd(&cursor[d], 1);
    adj[pos] = s;
}

// ---------------------------------------------------------------------------
// Pack BN-folded weights into MFMA B-fragment order, split bf16 hi/lo.
// Blocks 0..2: GIN layers. Block 3: head (lin1+bn folded, lin2 zero-padded).
// frag value: B[k = kk*32 + (lane>>4)*8 + j][n = ct*16 + (lane&15)]
// ---------------------------------------------------------------------------
__global__ void pack_kernel(const float* __restrict__ W1, const float* __restrict__ b1,
                            const float* __restrict__ g1, const float* __restrict__ bt1,
                            const float* __restrict__ m1, const float* __restrict__ v1,
                            const float* __restrict__ W2, const float* __restrict__ b2,
                            const float* __restrict__ gc, const float* __restrict__ bc,
                            const float* __restrict__ mc, const float* __restrict__ vc,
                            const float* __restrict__ l1W, const float* __restrict__ l1b,
                            const float* __restrict__ gbn, const float* __restrict__ bbn,
                            const float* __restrict__ mbn, const float* __restrict__ vbn,
                            const float* __restrict__ l2W, const float* __restrict__ l2b,
                            unsigned short* __restrict__ w1p, unsigned short* __restrict__ w2p,
                            float* __restrict__ bias1, float* __restrict__ bias2,
                            unsigned short* __restrict__ w1ph, unsigned short* __restrict__ w2ph,
                            float* __restrict__ bias1h, float* __restrict__ bias2h) {
    int l = blockIdx.x, t = threadIdx.x;
    if (l < 3) {
        const float* W1l = W1 + (size_t)l * 64 * 128;
        const float* W2l = W2 + (size_t)l * 128 * 64;
        if (t < 128) {
            float s = g1[l * 128 + t] * rsqrtf(v1[l * 128 + t] + BN_EPS);
            bias1[l * 128 + t] = (b1[l * 128 + t] - m1[l * 128 + t]) * s + bt1[l * 128 + t];
        }
        if (t < 64) {
            float s = gc[l * 64 + t] * rsqrtf(vc[l * 64 + t] + BN_EPS);
            bias2[l * 64 + t] = (b2[l * 64 + t] - mc[l * 64 + t]) * s + bc[l * 64 + t];
        }
        for (int idx = t; idx < 16384; idx += 256) {
            int j = idx & 7, lane = (idx >> 3) & 63, hl = (idx >> 9) & 1;
            int kk = (idx >> 10) & 1, ct = idx >> 11;
            int k = kk * 32 + (lane >> 4) * 8 + j;
            int nn = ct * 16 + (lane & 15);
            float s = g1[l * 128 + nn] * rsqrtf(v1[l * 128 + nn] + BN_EPS);
            float w = W1l[k * 128 + nn] * s;
            unsigned short hi = f2bf(w);
            w1p[(size_t)l * 16384 + idx] = hl ? f2bf(w - bf2f(hi)) : hi;
        }
        for (int idx = t; idx < 16384; idx += 256) {
            int j = idx & 7, lane = (idx >> 3) & 63, hl = (idx >> 9) & 1;
            int kk = (idx >> 10) & 3, ct = idx >> 12;
            int k = kk * 32 + (lane >> 4) * 8 + j;
            int nn = ct * 16 + (lane & 15);
            float s = gc[l * 64 + nn] * rsqrtf(vc[l * 64 + nn] + BN_EPS);
            float w = W2l[k * 64 + nn] * s;
            unsigned short hi = f2bf(w);
            w2p[(size_t)l * 16384 + idx] = hl ? f2bf(w - bf2f(hi)) : hi;
        }
    } else {
        // head: lin1 (64x64, BN-folded) and lin2 (64x40 zero-padded to 64)
        if (t < 64) {
            float s = gbn[t] * rsqrtf(vbn[t] + BN_EPS);
            bias1h[t] = (l1b[t] - mbn[t]) * s + bbn[t];
            bias2h[t] = (t < 40) ? l2b[t] : 0.0f;
        }
        for (int idx = t; idx < 8192; idx += 256) {
            int j = idx & 7, lane = (idx >> 3) & 63, hl = (idx >> 9) & 1;
            int kk = (idx >> 10) & 1, ct = idx >> 11;   // ct<4
            int k = kk * 32 + (lane >> 4) * 8 + j;
            int nn = ct * 16 + (lane & 15);
            float s = gbn[nn] * rsqrtf(vbn[nn] + BN_EPS);
            float w = l1W[k * 64 + nn] * s;
            unsigned short hi = f2bf(w);
            w1ph[idx] = hl ? f2bf(w - bf2f(hi)) : hi;
        }
        for (int idx = t; idx < 8192; idx += 256) {
            int j = idx & 7, lane = (idx >> 3) & 63, hl = (idx >> 9) & 1;
            int kk = (idx >> 10) & 1, ct = idx >> 11;
            int k = kk * 32 + (lane >> 4) * 8 + j;
            int nn = ct * 16 + (lane & 15);
            float w = (nn < 40) ? l2W[k * 40 + nn] : 0.0f;
            unsigned short hi = f2bf(w);
            w2ph[idx] = hl ? f2bf(w - bf2f(hi)) : hi;
        }
    }
}

// ---------------------------------------------------------------------------
// h[i] = x[i] + sum_{j in N(i)} x[j]; one wave per node; CSR neighbor list;
// 4 independent load chains; emits bf16 hi/lo split for the MFMA A-operand.
// ---------------------------------------------------------------------------
__global__ void gather_kernel(const float* __restrict__ x, const int* __restrict__ adj,
                              const int* __restrict__ offs, const int* __restrict__ deg,
                              unsigned short* __restrict__ hhi,
                              unsigned short* __restrict__ hlo, int n) {
    int gid = blockIdx.x * blockDim.x + threadIdx.x;
    int node = gid >> 6;
    if (node >= n) return;
    int lane = threadIdx.x & 63;
    int d = deg[node];
    int off = offs[node];
    float acc = x[(size_t)node * 64 + lane];        // self term (GIN eps=0)
    float a1 = 0.f, a2 = 0.f, a3 = 0.f;
    for (int base = 0; base < d; base += 64) {
        int m = d - base; if (m > 64) m = 64;
        int myslot = (lane < m) ? adj[off + base + lane] : 0;
        int c = 0;
        for (; c + 4 <= m; c += 4) {
            int s0 = __shfl(myslot, c, 64);
            int s1 = __shfl(myslot, c + 1, 64);
            int s2 = __shfl(myslot, c + 2, 64);
            int s3 = __shfl(myslot, c + 3, 64);
            acc += x[(size_t)s0 * 64 + lane];
            a1  += x[(size_t)s1 * 64 + lane];
            a2  += x[(size_t)s2 * 64 + lane];
            a3  += x[(size_t)s3 * 64 + lane];
        }
        for (; c < m; ++c) {
            int s = __shfl(myslot, c, 64);
            acc += x[(size_t)s * 64 + lane];
        }
    }
    acc += (a1 + a2) + a3;
    unsigned short hi = f2bf(acc);
    unsigned short lo = f2bf(acc - bf2f(hi));
    hhi[(size_t)node * 64 + lane] = hi;
    hlo[(size_t)node * 64 + lane] = lo;
}

// ---------------------------------------------------------------------------
// MFMA GIN MLP, split-bf16 (hi+lo, 3 products) == fp32-accurate.
// Block = 4 waves, one 16-node tile. Wave w owns stage-A col-tiles {2w,2w+1}
// and stage-B col-tile w. Weights live in registers (pre-packed frags).
// ---------------------------------------------------------------------------
__global__ __launch_bounds__(256)
void mlp_mfma(const unsigned short* __restrict__ hhi, const unsigned short* __restrict__ hlo,
              const unsigned short* __restrict__ w1p, const unsigned short* __restrict__ w2p,
              const float* __restrict__ bias1, const float* __restrict__ bias2,
              float* __restrict__ xout, int n) {
    __shared__ __attribute__((aligned(16))) unsigned short h2hi[16 * 136];
    __shared__ __attribute__((aligned(16))) unsigned short h2lo[16 * 136];

    const int t = threadIdx.x;
    const int wv = t >> 6, lane = t & 63;
    const int quad = lane >> 4, l16 = lane & 15;

    short8 w1f[2][2][2];   // [ct_local][kk][hi/lo]
#pragma unroll
    for (int c = 0; c < 2; ++c)
#pragma unroll
        for (int kk = 0; kk < 2; ++kk)
#pragma unroll
            for (int hl = 0; hl < 2; ++hl) {
                int ct = wv * 2 + c;
                w1f[c][kk][hl] = *(const short8*)&w1p[(size_t)(((ct * 2 + kk) * 2 + hl) * 64 + lane) * 8];
            }
    short8 w2f[4][2];      // [kk][hi/lo], ct = wv
#pragma unroll
    for (int kk = 0; kk < 4; ++kk)
#pragma unroll
        for (int hl = 0; hl < 2; ++hl)
            w2f[kk][hl] = *(const short8*)&w2p[(size_t)(((wv * 4 + kk) * 2 + hl) * 64 + lane) * 8];

    float b1v0 = bias1[(wv * 2 + 0) * 16 + l16];
    float b1v1 = bias1[(wv * 2 + 1) * 16 + l16];
    float b2v  = bias2[wv * 16 + l16];

    const int tile = blockIdx.x * 16;
    int arow = tile + l16;
    if (arow >= n) arow = n - 1;

    const unsigned short* hr = hhi + (size_t)arow * 64 + quad * 8;
    const unsigned short* lr = hlo + (size_t)arow * 64 + quad * 8;
    short8 ah0 = *(const short8*)hr;
    short8 ah1 = *(const short8*)(hr + 32);
    short8 al0 = *(const short8*)lr;
    short8 al1 = *(const short8*)(lr + 32);

    floatx4 accA0 = {0.f, 0.f, 0.f, 0.f};
    floatx4 accA1 = {0.f, 0.f, 0.f, 0.f};
    accA0 = MFMA16(ah0, w1f[0][0][0], accA0);
    accA0 = MFMA16(ah0, w1f[0][0][1], accA0);
    accA0 = MFMA16(al0, w1f[0][0][0], accA0);
    accA0 = MFMA16(ah1, w1f[0][1][0], accA0);
    accA0 = MFMA16(ah1, w1f[0][1][1], accA0);
    accA0 = MFMA16(al1, w1f[0][1][0], accA0);
    accA1 = MFMA16(ah0, w1f[1][0][0], accA1);
    accA1 = MFMA16(ah0, w1f[1][0][1], accA1);
    accA1 = MFMA16(al0, w1f[1][0][0], accA1);
    accA1 = MFMA16(ah1, w1f[1][1][0], accA1);
    accA1 = MFMA16(ah1, w1f[1][1][1], accA1);
    accA1 = MFMA16(al1, w1f[1][1][0], accA1);

#pragma unroll
    for (int r = 0; r < 4; ++r) {
        int node = quad * 4 + r;
        {
            float v = fmaxf(accA0[r] + b1v0, 0.f);
            unsigned short hi = f2bf(v);
            int col = (wv * 2 + 0) * 16 + l16;
            h2hi[node * 136 + col] = hi;
            h2lo[node * 136 + col] = f2bf(v - bf2f(hi));
        }
        {
            float v = fmaxf(accA1[r] + b1v1, 0.f);
            unsigned short hi = f2bf(v);
            int col = (wv * 2 + 1) * 16 + l16;
            h2hi[node * 136 + col] = hi;
            h2lo[node * 136 + col] = f2bf(v - bf2f(hi));
        }
    }
    __syncthreads();

    floatx4 accB = {0.f, 0.f, 0.f, 0.f};
#pragma unroll
    for (int kk = 0; kk < 4; ++kk) {
        short8 a2h = *(const short8*)&h2hi[l16 * 136 + kk * 32 + quad * 8];
        short8 a2l = *(const short8*)&h2lo[l16 * 136 + kk * 32 + quad * 8];
        accB = MFMA16(a2h, w2f[kk][0], accB);
        accB = MFMA16(a2h, w2f[kk][1], accB);
        accB = MFMA16(a2l, w2f[kk][0], accB);
    }
    int col2 = wv * 16 + l16;
#pragma unroll
    for (int r = 0; r < 4; ++r) {
        int node = tile + quad * 4 + r;
        if (node < n)
            xout[(size_t)node * 64 + col2] = fmaxf(accB[r] + b2v, 0.f);
    }
}

// ---------------------------------------------------------------------------
// MFMA head: relu(bn1(x@lin1+b)) @ lin2pad -> log_softmax(40).
// Block = 4 waves, one 16-node tile; wave w owns col-tile w for both stages.
// ---------------------------------------------------------------------------
__global__ __launch_bounds__(256)
void head_mfma(const float* __restrict__ xin,
               const unsigned short* __restrict__ w1ph, const unsigned short* __restrict__ w2ph,
               const float* __restrict__ bias1h, const float* __restrict__ bias2h,
               float* __restrict__ out, int n) {
    __shared__ __attribute__((aligned(16))) unsigned short h2hi[16 * 72];
    __shared__ __attribute__((aligned(16))) unsigned short h2lo[16 * 72];
    __shared__ float zbuf[16][68];

    const int t = threadIdx.x;
    const int wv = t >> 6, lane = t & 63;
    const int quad = lane >> 4, l16 = lane & 15;

    short8 w1f[2][2];  // [kk][hi/lo], ct = wv
    short8 w2f[2][2];
#pragma unroll
    for (int kk = 0; kk < 2; ++kk)
#pragma unroll
        for (int hl = 0; hl < 2; ++hl) {
            w1f[kk][hl] = *(const short8*)&w1ph[(size_t)(((wv * 2 + kk) * 2 + hl) * 64 + lane) * 8];
            w2f[kk][hl] = *(const short8*)&w2ph[(size_t)(((wv * 2 + kk) * 2 + hl) * 64 + lane) * 8];
        }
    float b1v = bias1h[wv * 16 + l16];
    float b2v = bias2h[wv * 16 + l16];

    const int tile = blockIdx.x * 16;
    int arow = tile + l16;
    if (arow >= n) arow = n - 1;

    // A-frags from fp32 input, split hi/lo
    short8 ah[2], al[2];
#pragma unroll
    for (int kk = 0; kk < 2; ++kk) {
        const float* xr = xin + (size_t)arow * 64 + kk * 32 + quad * 8;
        float4 xa = *(const float4*)xr;
        float4 xb = *(const float4*)(xr + 4);
        float v[8] = {xa.x, xa.y, xa.z, xa.w, xb.x, xb.y, xb.z, xb.w};
#pragma unroll
        for (int j = 0; j < 8; ++j) {
            unsigned short hi = f2bf(v[j]);
            ah[kk][j] = (short)hi;
            al[kk][j] = (short)f2bf(v[j] - bf2f(hi));
        }
    }

    floatx4 accA = {0.f, 0.f, 0.f, 0.f};
#pragma unroll
    for (int kk = 0; kk < 2; ++kk) {
        accA = MFMA16(ah[kk], w1f[kk][0], accA);
        accA = MFMA16(ah[kk], w1f[kk][1], accA);
        accA = MFMA16(al[kk], w1f[kk][0], accA);
    }
#pragma unroll
    for (int r = 0; r < 4; ++r) {
        int node = quad * 4 + r;
        float v = fmaxf(accA[r] + b1v, 0.f);
        unsigned short hi = f2bf(v);
        int col = wv * 16 + l16;
        h2hi[node * 72 + col] = hi;
        h2lo[node * 72 + col] = f2bf(v - bf2f(hi));
    }
    __syncthreads();

    floatx4 accB = {0.f, 0.f, 0.f, 0.f};
#pragma unroll
    for (int kk = 0; kk < 2; ++kk) {
        short8 a2h = *(const short8*)&h2hi[l16 * 72 + kk * 32 + quad * 8];
        short8 a2l = *(const short8*)&h2lo[l16 * 72 + kk * 32 + quad * 8];
        accB = MFMA16(a2h, w2f[kk][0], accB);
        accB = MFMA16(a2h, w2f[kk][1], accB);
        accB = MFMA16(a2l, w2f[kk][0], accB);
    }
#pragma unroll
    for (int r = 0; r < 4; ++r)
        zbuf[quad * 4 + r][wv * 16 + l16] = accB[r] + b2v;
    __syncthreads();

    // log-softmax: wave wv handles nodes wv*4 .. wv*4+3; lanes 0..39 = classes
#pragma unroll
    for (int r = 0; r < 4; ++r) {
        int nl = wv * 4 + r;
        float zi = (lane < 40) ? zbuf[nl][lane] : -INFINITY;
        float mx = zi;
#pragma unroll
        for (int msk = 1; msk < 64; msk <<= 1)
            mx = fmaxf(mx, __shfl_xor(mx, msk, 64));
        float e = (lane < 40) ? __expf(zi - mx) : 0.f;
        float se = e;
#pragma unroll
        for (int msk = 1; msk < 64; msk <<= 1)
            se += __shfl_xor(se, msk, 64);
        float lse = mx + __logf(se);
        int node = tile + nl;
        if (lane < 40 && node < n)
            out[(size_t)node * 40 + lane] = zi - lse;
    }
}

// ---------------------------------------------------------------------------
extern "C" void kernel_launch(void* const* d_in, const int* in_sizes, int n_in,
                              void* d_out, int out_size, void* d_ws, size_t ws_size,
                              hipStream_t stream) {
    const float* x    = (const float*)d_in[0];
    const int*   ei   = (const int*)d_in[1];
    const float* W1   = (const float*)d_in[2];
    const float* b1   = (const float*)d_in[3];
    const float* g1   = (const float*)d_in[4];
    const float* bt1  = (const float*)d_in[5];
    const float* m1   = (const float*)d_in[6];
    const float* v1   = (const float*)d_in[7];
    const float* W2   = (const float*)d_in[8];
    const float* b2   = (const float*)d_in[9];
    const float* gc   = (const float*)d_in[10];
    const float* bc   = (const float*)d_in[11];
    const float* mc   = (const float*)d_in[12];
    const float* vc   = (const float*)d_in[13];
    const float* l1W  = (const float*)d_in[14];
    const float* l1b  = (const float*)d_in[15];
    const float* gbn  = (const float*)d_in[16];
    const float* bbn  = (const float*)d_in[17];
    const float* mbn  = (const float*)d_in[18];
    const float* vbn  = (const float*)d_in[19];
    const float* l2W  = (const float*)d_in[20];
    const float* l2b  = (const float*)d_in[21];
    float* out = (float*)d_out;

    int N = in_sizes[0] / 64;
    int E = in_sizes[1] / 2;

    char* w = (char*)d_ws;
    int* deg = (int*)w;              w += ((size_t)N * 4 + 255) / 256 * 256;
    int* offs = (int*)w;             w += ((size_t)N * 4 + 255) / 256 * 256;
    int* cursor = (int*)w;           w += ((size_t)N * 4 + 255) / 256 * 256;
    int* counter = (int*)w;          w += 256;
    int* adj = (int*)w;              w += ((size_t)E * 4 + 255) / 256 * 256;
    unsigned short* hhi = (unsigned short*)w;  w += (size_t)N * 64 * 2;
    unsigned short* hlo = (unsigned short*)w;  w += (size_t)N * 64 * 2;
    float* xb0 = (float*)w;          w += (size_t)N * 64 * 4;
    unsigned short* w1p = (unsigned short*)w;  w += 3 * 16384 * 2;
    unsigned short* w2p = (unsigned short*)w;  w += 3 * 16384 * 2;
    float* bias1 = (float*)w;        w += 3 * 128 * 4;
    float* bias2 = (float*)w;        w += 3 * 64 * 4;
    unsigned short* w1ph = (unsigned short*)w; w += 8192 * 2;
    unsigned short* w2ph = (unsigned short*)w; w += 8192 * 2;
    float* bias1h = (float*)w;       w += 64 * 4;
    float* bias2h = (float*)w;       w += 64 * 4;

    hipMemsetAsync(deg, 0, (size_t)N * 4, stream);
    hipMemsetAsync(counter, 0, 256, stream);
    hist_kernel<<<(E + 255) / 256, 256, 0, stream>>>(ei, deg, E);
    alloc_kernel<<<(N + 255) / 256, 256, 0, stream>>>(deg, offs, cursor, counter, N);
    scatter_kernel<<<(E + 255) / 256, 256, 0, stream>>>(ei, cursor, adj, E);
    pack_kernel<<<4, 256, 0, stream>>>(W1, b1, g1, bt1, m1, v1, W2, b2, gc, bc, mc, vc,
                                       l1W, l1b, gbn, bbn, mbn, vbn, l2W, l2b,
                                       w1p, w2p, bias1, bias2, w1ph, w2ph, bias1h, bias2h);

    const float* cur = x;
    int nblk = (N + 15) / 16;
    for (int l = 0; l < 3; ++l) {
        gather_kernel<<<(N * 64 + 255) / 256, 256, 0, stream>>>(cur, adj, offs, deg, hhi, hlo, N);
        mlp_mfma<<<nblk, 256, 0, stream>>>(hhi, hlo,
                                           w1p + (size_t)l * 16384, w2p + (size_t)l * 16384,
                                           bias1 + (size_t)l * 128, bias2 + (size_t)l * 64,
                                           xb0, N);
        cur = xb0;
    }
    head_mfma<<<nblk, 256, 0, stream>>>(xb0, w1ph, w2ph, bias1h, bias2h, out, N);
}

// Round 5
// 389.431 us; speedup vs baseline: 1.2866x; 1.0345x over previous
//
#include <hip/hip_runtime.h>
#include <math.h>

#define BN_EPS 1e-5f

typedef short short8 __attribute__((ext_vector_type(8)));
typedef float floatx4 __attribute__((ext_vector_type(4)));

#define MFMA16(a, b, c) __builtin_amdgcn_mfma_f32_16x16x32_bf16((a), (b), (c), 0, 0, 0)

// fp32 -> bf16 bits, round-to-nearest-even
__device__ __forceinline__ unsigned short f2bf(float x) {
    unsigned u = __float_as_uint(x);
    u = u + 0x7fffu + ((u >> 16) & 1u);
    return (unsigned short)(u >> 16);
}
__device__ __forceinline__ float bf2f(unsigned short b) {
    return __uint_as_float(((unsigned)b) << 16);
}

// ---------------------------------------------------------------------------
// CSR build, pass 1: degree histogram, XCD-partitioned by dst range.
// blockIdx%8 ~ XCD (round-robin dispatch); slice lines dirty in ONE L2 only.
// ---------------------------------------------------------------------------
__global__ void hist_kernel(const int* __restrict__ ei, int* __restrict__ deg,
                            int E, int n) {
    int part = blockIdx.x & 7;
    int lo = (int)((long long)part * n >> 3);
    int hi = (int)((long long)(part + 1) * n >> 3);
    int stride = (gridDim.x >> 3) * 256;
    for (int e = (blockIdx.x >> 3) * 256 + threadIdx.x; e < E; e += stride) {
        int d = ei[E + e];
        if (d >= lo && d < hi) atomicAdd(&deg[d], 1);
    }
}

// ---------------------------------------------------------------------------
// CSR build, pass 2: range ALLOCATION (node order irrelevant).
// Wave prefix over degrees + one atomicAdd per wave.
// ---------------------------------------------------------------------------
__global__ void alloc_kernel(const int* __restrict__ deg, int* __restrict__ offs,
                             int* __restrict__ cursor, int* __restrict__ counter, int n) {
    int i = blockIdx.x * 256 + threadIdx.x;
    int lane = threadIdx.x & 63;
    int d = (i < n) ? deg[i] : 0;
    int pre = d;
#pragma unroll
    for (int delta = 1; delta < 64; delta <<= 1) {
        int v = __shfl_up(pre, delta, 64);
        if (lane >= delta) pre += v;
    }
    int total = __shfl(pre, 63, 64);   // wave sum
    int excl = pre - d;                // exclusive prefix within wave
    int base = 0;
    if (lane == 0) base = atomicAdd(counter, total);
    base = __shfl(base, 0, 64);
    if (i < n) {
        offs[i] = base + excl;
        cursor[i] = base + excl;
    }
}

// ---------------------------------------------------------------------------
// CSR build, pass 3: scatter, XCD-partitioned by dst range (same key as hist).
// cursor/adj lines for a slice are written by one XCD -> no x8 write-back.
// ---------------------------------------------------------------------------
__global__ void scatter_kernel(const int* __restrict__ ei, int* __restrict__ cursor,
                               int* __restrict__ adj, int E, int n) {
    int part = blockIdx.x & 7;
    int lo = (int)((long long)part * n >> 3);
    int hi = (int)((long long)(part + 1) * n >> 3);
    int stride = (gridDim.x >> 3) * 256;
    for (int e = (blockIdx.x >> 3) * 256 + threadIdx.x; e < E; e += stride) {
        int d = ei[E + e];
        if (d >= lo && d < hi) {
            int pos = atomicAdd(&cursor[d], 1);
            adj[pos] = ei[e];
        }
    }
}

// ---------------------------------------------------------------------------
// Pack BN-folded weights into MFMA B-fragment order, split bf16 hi/lo.
// Blocks 0..2: GIN layers. Block 3: head (lin1+bn folded, lin2 zero-padded).
// frag value: B[k = kk*32 + (lane>>4)*8 + j][n = ct*16 + (lane&15)]
// ---------------------------------------------------------------------------
__global__ void pack_kernel(const float* __restrict__ W1, const float* __restrict__ b1,
                            const float* __restrict__ g1, const float* __restrict__ bt1,
                            const float* __restrict__ m1, const float* __restrict__ v1,
                            const float* __restrict__ W2, const float* __restrict__ b2,
                            const float* __restrict__ gc, const float* __restrict__ bc,
                            const float* __restrict__ mc, const float* __restrict__ vc,
                            const float* __restrict__ l1W, const float* __restrict__ l1b,
                            const float* __restrict__ gbn, const float* __restrict__ bbn,
                            const float* __restrict__ mbn, const float* __restrict__ vbn,
                            const float* __restrict__ l2W, const float* __restrict__ l2b,
                            unsigned short* __restrict__ w1p, unsigned short* __restrict__ w2p,
                            float* __restrict__ bias1, float* __restrict__ bias2,
                            unsigned short* __restrict__ w1ph, unsigned short* __restrict__ w2ph,
                            float* __restrict__ bias1h, float* __restrict__ bias2h) {
    int l = blockIdx.x, t = threadIdx.x;
    if (l < 3) {
        const float* W1l = W1 + (size_t)l * 64 * 128;
        const float* W2l = W2 + (size_t)l * 128 * 64;
        if (t < 128) {
            float s = g1[l * 128 + t] * rsqrtf(v1[l * 128 + t] + BN_EPS);
            bias1[l * 128 + t] = (b1[l * 128 + t] - m1[l * 128 + t]) * s + bt1[l * 128 + t];
        }
        if (t < 64) {
            float s = gc[l * 64 + t] * rsqrtf(vc[l * 64 + t] + BN_EPS);
            bias2[l * 64 + t] = (b2[l * 64 + t] - mc[l * 64 + t]) * s + bc[l * 64 + t];
        }
        for (int idx = t; idx < 16384; idx += 256) {
            int j = idx & 7, lane = (idx >> 3) & 63, hl = (idx >> 9) & 1;
            int kk = (idx >> 10) & 1, ct = idx >> 11;
            int k = kk * 32 + (lane >> 4) * 8 + j;
            int nn = ct * 16 + (lane & 15);
            float s = g1[l * 128 + nn] * rsqrtf(v1[l * 128 + nn] + BN_EPS);
            float w = W1l[k * 128 + nn] * s;
            unsigned short hi = f2bf(w);
            w1p[(size_t)l * 16384 + idx] = hl ? f2bf(w - bf2f(hi)) : hi;
        }
        for (int idx = t; idx < 16384; idx += 256) {
            int j = idx & 7, lane = (idx >> 3) & 63, hl = (idx >> 9) & 1;
            int kk = (idx >> 10) & 3, ct = idx >> 12;
            int k = kk * 32 + (lane >> 4) * 8 + j;
            int nn = ct * 16 + (lane & 15);
            float s = gc[l * 64 + nn] * rsqrtf(vc[l * 64 + nn] + BN_EPS);
            float w = W2l[k * 64 + nn] * s;
            unsigned short hi = f2bf(w);
            w2p[(size_t)l * 16384 + idx] = hl ? f2bf(w - bf2f(hi)) : hi;
        }
    } else {
        // head: lin1 (64x64, BN-folded) and lin2 (64x40 zero-padded to 64)
        if (t < 64) {
            float s = gbn[t] * rsqrtf(vbn[t] + BN_EPS);
            bias1h[t] = (l1b[t] - mbn[t]) * s + bbn[t];
            bias2h[t] = (t < 40) ? l2b[t] : 0.0f;
        }
        for (int idx = t; idx < 8192; idx += 256) {
            int j = idx & 7, lane = (idx >> 3) & 63, hl = (idx >> 9) & 1;
            int kk = (idx >> 10) & 1, ct = idx >> 11;   // ct<4
            int k = kk * 32 + (lane >> 4) * 8 + j;
            int nn = ct * 16 + (lane & 15);
            float s = gbn[nn] * rsqrtf(vbn[nn] + BN_EPS);
            float w = l1W[k * 64 + nn] * s;
            unsigned short hi = f2bf(w);
            w1ph[idx] = hl ? f2bf(w - bf2f(hi)) : hi;
        }
        for (int idx = t; idx < 8192; idx += 256) {
            int j = idx & 7, lane = (idx >> 3) & 63, hl = (idx >> 9) & 1;
            int kk = (idx >> 10) & 1, ct = idx >> 11;
            int k = kk * 32 + (lane >> 4) * 8 + j;
            int nn = ct * 16 + (lane & 15);
            float w = (nn < 40) ? l2W[k * 40 + nn] : 0.0f;
            unsigned short hi = f2bf(w);
            w2ph[idx] = hl ? f2bf(w - bf2f(hi)) : hi;
        }
    }
}

// ---------------------------------------------------------------------------
// h[i] = x[i] + sum_{j in N(i)} x[j]; one wave per node; CSR neighbor list;
// 4 independent load chains; emits bf16 hi/lo split for the MFMA A-operand.
// ---------------------------------------------------------------------------
__global__ void gather_kernel(const float* __restrict__ x, const int* __restrict__ adj,
                              const int* __restrict__ offs, const int* __restrict__ deg,
                              unsigned short* __restrict__ hhi,
                              unsigned short* __restrict__ hlo, int n) {
    int gid = blockIdx.x * blockDim.x + threadIdx.x;
    int node = gid >> 6;
    if (node >= n) return;
    int lane = threadIdx.x & 63;
    int d = deg[node];
    int off = offs[node];
    float acc = x[(size_t)node * 64 + lane];        // self term (GIN eps=0)
    float a1 = 0.f, a2 = 0.f, a3 = 0.f;
    for (int base = 0; base < d; base += 64) {
        int m = d - base; if (m > 64) m = 64;
        int myslot = (lane < m) ? adj[off + base + lane] : 0;
        int c = 0;
        for (; c + 4 <= m; c += 4) {
            int s0 = __shfl(myslot, c, 64);
            int s1 = __shfl(myslot, c + 1, 64);
            int s2 = __shfl(myslot, c + 2, 64);
            int s3 = __shfl(myslot, c + 3, 64);
            acc += x[(size_t)s0 * 64 + lane];
            a1  += x[(size_t)s1 * 64 + lane];
            a2  += x[(size_t)s2 * 64 + lane];
            a3  += x[(size_t)s3 * 64 + lane];
        }
        for (; c < m; ++c) {
            int s = __shfl(myslot, c, 64);
            acc += x[(size_t)s * 64 + lane];
        }
    }
    acc += (a1 + a2) + a3;
    unsigned short hi = f2bf(acc);
    unsigned short lo = f2bf(acc - bf2f(hi));
    hhi[(size_t)node * 64 + lane] = hi;
    hlo[(size_t)node * 64 + lane] = lo;
}

// ---------------------------------------------------------------------------
// MFMA GIN MLP, split-bf16 (hi+lo, 3 products) == fp32-accurate.
// Block = 4 waves, one 16-node tile. Wave w owns stage-A col-tiles {2w,2w+1}
// and stage-B col-tile w. Weights live in registers (pre-packed frags).
// ---------------------------------------------------------------------------
__global__ __launch_bounds__(256)
void mlp_mfma(const unsigned short* __restrict__ hhi, const unsigned short* __restrict__ hlo,
              const unsigned short* __restrict__ w1p, const unsigned short* __restrict__ w2p,
              const float* __restrict__ bias1, const float* __restrict__ bias2,
              float* __restrict__ xout, int n) {
    __shared__ __attribute__((aligned(16))) unsigned short h2hi[16 * 136];
    __shared__ __attribute__((aligned(16))) unsigned short h2lo[16 * 136];

    const int t = threadIdx.x;
    const int wv = t >> 6, lane = t & 63;
    const int quad = lane >> 4, l16 = lane & 15;

    short8 w1f[2][2][2];   // [ct_local][kk][hi/lo]
#pragma unroll
    for (int c = 0; c < 2; ++c)
#pragma unroll
        for (int kk = 0; kk < 2; ++kk)
#pragma unroll
            for (int hl = 0; hl < 2; ++hl) {
                int ct = wv * 2 + c;
                w1f[c][kk][hl] = *(const short8*)&w1p[(size_t)(((ct * 2 + kk) * 2 + hl) * 64 + lane) * 8];
            }
    short8 w2f[4][2];      // [kk][hi/lo], ct = wv
#pragma unroll
    for (int kk = 0; kk < 4; ++kk)
#pragma unroll
        for (int hl = 0; hl < 2; ++hl)
            w2f[kk][hl] = *(const short8*)&w2p[(size_t)(((wv * 4 + kk) * 2 + hl) * 64 + lane) * 8];

    float b1v0 = bias1[(wv * 2 + 0) * 16 + l16];
    float b1v1 = bias1[(wv * 2 + 1) * 16 + l16];
    float b2v  = bias2[wv * 16 + l16];

    const int tile = blockIdx.x * 16;
    int arow = tile + l16;
    if (arow >= n) arow = n - 1;

    const unsigned short* hr = hhi + (size_t)arow * 64 + quad * 8;
    const unsigned short* lr = hlo + (size_t)arow * 64 + quad * 8;
    short8 ah0 = *(const short8*)hr;
    short8 ah1 = *(const short8*)(hr + 32);
    short8 al0 = *(const short8*)lr;
    short8 al1 = *(const short8*)(lr + 32);

    floatx4 accA0 = {0.f, 0.f, 0.f, 0.f};
    floatx4 accA1 = {0.f, 0.f, 0.f, 0.f};
    accA0 = MFMA16(ah0, w1f[0][0][0], accA0);
    accA0 = MFMA16(ah0, w1f[0][0][1], accA0);
    accA0 = MFMA16(al0, w1f[0][0][0], accA0);
    accA0 = MFMA16(ah1, w1f[0][1][0], accA0);
    accA0 = MFMA16(ah1, w1f[0][1][1], accA0);
    accA0 = MFMA16(al1, w1f[0][1][0], accA0);
    accA1 = MFMA16(ah0, w1f[1][0][0], accA1);
    accA1 = MFMA16(ah0, w1f[1][0][1], accA1);
    accA1 = MFMA16(al0, w1f[1][0][0], accA1);
    accA1 = MFMA16(ah1, w1f[1][1][0], accA1);
    accA1 = MFMA16(ah1, w1f[1][1][1], accA1);
    accA1 = MFMA16(al1, w1f[1][1][0], accA1);

#pragma unroll
    for (int r = 0; r < 4; ++r) {
        int node = quad * 4 + r;
        {
            float v = fmaxf(accA0[r] + b1v0, 0.f);
            unsigned short hi = f2bf(v);
            int col = (wv * 2 + 0) * 16 + l16;
            h2hi[node * 136 + col] = hi;
            h2lo[node * 136 + col] = f2bf(v - bf2f(hi));
        }
        {
            float v = fmaxf(accA1[r] + b1v1, 0.f);
            unsigned short hi = f2bf(v);
            int col = (wv * 2 + 1) * 16 + l16;
            h2hi[node * 136 + col] = hi;
            h2lo[node * 136 + col] = f2bf(v - bf2f(hi));
        }
    }
    __syncthreads();

    floatx4 accB = {0.f, 0.f, 0.f, 0.f};
#pragma unroll
    for (int kk = 0; kk < 4; ++kk) {
        short8 a2h = *(const short8*)&h2hi[l16 * 136 + kk * 32 + quad * 8];
        short8 a2l = *(const short8*)&h2lo[l16 * 136 + kk * 32 + quad * 8];
        accB = MFMA16(a2h, w2f[kk][0], accB);
        accB = MFMA16(a2h, w2f[kk][1], accB);
        accB = MFMA16(a2l, w2f[kk][0], accB);
    }
    int col2 = wv * 16 + l16;
#pragma unroll
    for (int r = 0; r < 4; ++r) {
        int node = tile + quad * 4 + r;
        if (node < n)
            xout[(size_t)node * 64 + col2] = fmaxf(accB[r] + b2v, 0.f);
    }
}

// ---------------------------------------------------------------------------
// MFMA head: relu(bn1(x@lin1+b)) @ lin2pad -> log_softmax(40).
// Block = 4 waves, one 16-node tile; wave w owns col-tile w for both stages.
// ---------------------------------------------------------------------------
__global__ __launch_bounds__(256)
void head_mfma(const float* __restrict__ xin,
               const unsigned short* __restrict__ w1ph, const unsigned short* __restrict__ w2ph,
               const float* __restrict__ bias1h, const float* __restrict__ bias2h,
               float* __restrict__ out, int n) {
    __shared__ __attribute__((aligned(16))) unsigned short h2hi[16 * 72];
    __shared__ __attribute__((aligned(16))) unsigned short h2lo[16 * 72];
    __shared__ float zbuf[16][68];

    const int t = threadIdx.x;
    const int wv = t >> 6, lane = t & 63;
    const int quad = lane >> 4, l16 = lane & 15;

    short8 w1f[2][2];  // [kk][hi/lo], ct = wv
    short8 w2f[2][2];
#pragma unroll
    for (int kk = 0; kk < 2; ++kk)
#pragma unroll
        for (int hl = 0; hl < 2; ++hl) {
            w1f[kk][hl] = *(const short8*)&w1ph[(size_t)(((wv * 2 + kk) * 2 + hl) * 64 + lane) * 8];
            w2f[kk][hl] = *(const short8*)&w2ph[(size_t)(((wv * 2 + kk) * 2 + hl) * 64 + lane) * 8];
        }
    float b1v = bias1h[wv * 16 + l16];
    float b2v = bias2h[wv * 16 + l16];

    const int tile = blockIdx.x * 16;
    int arow = tile + l16;
    if (arow >= n) arow = n - 1;

    // A-frags from fp32 input, split hi/lo
    short8 ah[2], al[2];
#pragma unroll
    for (int kk = 0; kk < 2; ++kk) {
        const float* xr = xin + (size_t)arow * 64 + kk * 32 + quad * 8;
        float4 xa = *(const float4*)xr;
        float4 xb = *(const float4*)(xr + 4);
        float v[8] = {xa.x, xa.y, xa.z, xa.w, xb.x, xb.y, xb.z, xb.w};
#pragma unroll
        for (int j = 0; j < 8; ++j) {
            unsigned short hi = f2bf(v[j]);
            ah[kk][j] = (short)hi;
            al[kk][j] = (short)f2bf(v[j] - bf2f(hi));
        }
    }

    floatx4 accA = {0.f, 0.f, 0.f, 0.f};
#pragma unroll
    for (int kk = 0; kk < 2; ++kk) {
        accA = MFMA16(ah[kk], w1f[kk][0], accA);
        accA = MFMA16(ah[kk], w1f[kk][1], accA);
        accA = MFMA16(al[kk], w1f[kk][0], accA);
    }
#pragma unroll
    for (int r = 0; r < 4; ++r) {
        int node = quad * 4 + r;
        float v = fmaxf(accA[r] + b1v, 0.f);
        unsigned short hi = f2bf(v);
        int col = wv * 16 + l16;
        h2hi[node * 72 + col] = hi;
        h2lo[node * 72 + col] = f2bf(v - bf2f(hi));
    }
    __syncthreads();

    floatx4 accB = {0.f, 0.f, 0.f, 0.f};
#pragma unroll
    for (int kk = 0; kk < 2; ++kk) {
        short8 a2h = *(const short8*)&h2hi[l16 * 72 + kk * 32 + quad * 8];
        short8 a2l = *(const short8*)&h2lo[l16 * 72 + kk * 32 + quad * 8];
        accB = MFMA16(a2h, w2f[kk][0], accB);
        accB = MFMA16(a2h, w2f[kk][1], accB);
        accB = MFMA16(a2l, w2f[kk][0], accB);
    }
#pragma unroll
    for (int r = 0; r < 4; ++r)
        zbuf[quad * 4 + r][wv * 16 + l16] = accB[r] + b2v;
    __syncthreads();

    // log-softmax: wave wv handles nodes wv*4 .. wv*4+3; lanes 0..39 = classes
#pragma unroll
    for (int r = 0; r < 4; ++r) {
        int nl = wv * 4 + r;
        float zi = (lane < 40) ? zbuf[nl][lane] : -INFINITY;
        float mx = zi;
#pragma unroll
        for (int msk = 1; msk < 64; msk <<= 1)
            mx = fmaxf(mx, __shfl_xor(mx, msk, 64));
        float e = (lane < 40) ? __expf(zi - mx) : 0.f;
        float se = e;
#pragma unroll
        for (int msk = 1; msk < 64; msk <<= 1)
            se += __shfl_xor(se, msk, 64);
        float lse = mx + __logf(se);
        int node = tile + nl;
        if (lane < 40 && node < n)
            out[(size_t)node * 40 + lane] = zi - lse;
    }
}

// ---------------------------------------------------------------------------
extern "C" void kernel_launch(void* const* d_in, const int* in_sizes, int n_in,
                              void* d_out, int out_size, void* d_ws, size_t ws_size,
                              hipStream_t stream) {
    const float* x    = (const float*)d_in[0];
    const int*   ei   = (const int*)d_in[1];
    const float* W1   = (const float*)d_in[2];
    const float* b1   = (const float*)d_in[3];
    const float* g1   = (const float*)d_in[4];
    const float* bt1  = (const float*)d_in[5];
    const float* m1   = (const float*)d_in[6];
    const float* v1   = (const float*)d_in[7];
    const float* W2   = (const float*)d_in[8];
    const float* b2   = (const float*)d_in[9];
    const float* gc   = (const float*)d_in[10];
    const float* bc   = (const float*)d_in[11];
    const float* mc   = (const float*)d_in[12];
    const float* vc   = (const float*)d_in[13];
    const float* l1W  = (const float*)d_in[14];
    const float* l1b  = (const float*)d_in[15];
    const float* gbn  = (const float*)d_in[16];
    const float* bbn  = (const float*)d_in[17];
    const float* mbn  = (const float*)d_in[18];
    const float* vbn  = (const float*)d_in[19];
    const float* l2W  = (const float*)d_in[20];
    const float* l2b  = (const float*)d_in[21];
    float* out = (float*)d_out;

    int N = in_sizes[0] / 64;
    int E = in_sizes[1] / 2;

    char* w = (char*)d_ws;
    int* deg = (int*)w;              w += ((size_t)N * 4 + 255) / 256 * 256;
    int* offs = (int*)w;             w += ((size_t)N * 4 + 255) / 256 * 256;
    int* cursor = (int*)w;           w += ((size_t)N * 4 + 255) / 256 * 256;
    int* counter = (int*)w;          w += 256;
    int* adj = (int*)w;              w += ((size_t)E * 4 + 255) / 256 * 256;
    unsigned short* hhi = (unsigned short*)w;  w += (size_t)N * 64 * 2;
    unsigned short* hlo = (unsigned short*)w;  w += (size_t)N * 64 * 2;
    float* xb0 = (float*)w;          w += (size_t)N * 64 * 4;
    unsigned short* w1p = (unsigned short*)w;  w += 3 * 16384 * 2;
    unsigned short* w2p = (unsigned short*)w;  w += 3 * 16384 * 2;
    float* bias1 = (float*)w;        w += 3 * 128 * 4;
    float* bias2 = (float*)w;        w += 3 * 64 * 4;
    unsigned short* w1ph = (unsigned short*)w; w += 8192 * 2;
    unsigned short* w2ph = (unsigned short*)w; w += 8192 * 2;
    float* bias1h = (float*)w;       w += 64 * 4;
    float* bias2h = (float*)w;       w += 64 * 4;

    hipMemsetAsync(deg, 0, (size_t)N * 4, stream);
    hipMemsetAsync(counter, 0, 256, stream);
    // 8 partitions x 256 chunks = 2048 blocks
    hist_kernel<<<2048, 256, 0, stream>>>(ei, deg, E, N);
    alloc_kernel<<<(N + 255) / 256, 256, 0, stream>>>(deg, offs, cursor, counter, N);
    scatter_kernel<<<2048, 256, 0, stream>>>(ei, cursor, adj, E, N);
    pack_kernel<<<4, 256, 0, stream>>>(W1, b1, g1, bt1, m1, v1, W2, b2, gc, bc, mc, vc,
                                       l1W, l1b, gbn, bbn, mbn, vbn, l2W, l2b,
                                       w1p, w2p, bias1, bias2, w1ph, w2ph, bias1h, bias2h);

    const float* cur = x;
    int nblk = (N + 15) / 16;
    for (int l = 0; l < 3; ++l) {
        gather_kernel<<<(N * 64 + 255) / 256, 256, 0, stream>>>(cur, adj, offs, deg, hhi, hlo, N);
        mlp_mfma<<<nblk, 256, 0, stream>>>(hhi, hlo,
                                           w1p + (size_t)l * 16384, w2p + (size_t)l * 16384,
                                           bias1 + (size_t)l * 128, bias2 + (size_t)l * 64,
                                           xb0, N);
        cur = xb0;
    }
    head_mfma<<<nblk, 256, 0, stream>>>(xb0, w1ph, w2ph, bias1h, bias2h, out, N);
}

// Round 6
// 349.809 us; speedup vs baseline: 1.4323x; 1.1133x over previous
//
#include <hip/hip_runtime.h>
#include <math.h>

#define BN_EPS 1e-5f

typedef short short8 __attribute__((ext_vector_type(8)));
typedef float floatx4 __attribute__((ext_vector_type(4)));

#define MFMA16(a, b, c) __builtin_amdgcn_mfma_f32_16x16x32_bf16((a), (b), (c), 0, 0, 0)

// fp32 -> bf16 bits, round-to-nearest-even
__device__ __forceinline__ unsigned short f2bf(float x) {
    unsigned u = __float_as_uint(x);
    u = u + 0x7fffu + ((u >> 16) & 1u);
    return (unsigned short)(u >> 16);
}
__device__ __forceinline__ float bf2f(unsigned short b) {
    return __uint_as_float(((unsigned)b) << 16);
}

// ---------------------------------------------------------------------------
// CSR build, pass 1: degree histogram, XCD-partitioned by dst range.
// blockIdx%8 ~ XCD (round-robin dispatch); slice lines dirty in ONE L2 only.
// ---------------------------------------------------------------------------
__global__ void hist_kernel(const int* __restrict__ ei, int* __restrict__ deg,
                            int E, int n) {
    int part = blockIdx.x & 7;
    int lo = (int)((long long)part * n >> 3);
    int hi = (int)((long long)(part + 1) * n >> 3);
    int stride = (gridDim.x >> 3) * 256;
    for (int e = (blockIdx.x >> 3) * 256 + threadIdx.x; e < E; e += stride) {
        int d = ei[E + e];
        if (d >= lo && d < hi) atomicAdd(&deg[d], 1);
    }
}

// ---------------------------------------------------------------------------
// CSR build, pass 2: range ALLOCATION (node order irrelevant).
// Wave prefix over degrees + one atomicAdd per wave.
// ---------------------------------------------------------------------------
__global__ void alloc_kernel(const int* __restrict__ deg, int* __restrict__ offs,
                             int* __restrict__ cursor, int* __restrict__ counter, int n) {
    int i = blockIdx.x * 256 + threadIdx.x;
    int lane = threadIdx.x & 63;
    int d = (i < n) ? deg[i] : 0;
    int pre = d;
#pragma unroll
    for (int delta = 1; delta < 64; delta <<= 1) {
        int v = __shfl_up(pre, delta, 64);
        if (lane >= delta) pre += v;
    }
    int total = __shfl(pre, 63, 64);   // wave sum
    int excl = pre - d;                // exclusive prefix within wave
    int base = 0;
    if (lane == 0) base = atomicAdd(counter, total);
    base = __shfl(base, 0, 64);
    if (i < n) {
        offs[i] = base + excl;
        cursor[i] = base + excl;
    }
}

// ---------------------------------------------------------------------------
// CSR build, pass 3: scatter, XCD-partitioned by dst range (same key as hist).
// ---------------------------------------------------------------------------
__global__ void scatter_kernel(const int* __restrict__ ei, int* __restrict__ cursor,
                               int* __restrict__ adj, int E, int n) {
    int part = blockIdx.x & 7;
    int lo = (int)((long long)part * n >> 3);
    int hi = (int)((long long)(part + 1) * n >> 3);
    int stride = (gridDim.x >> 3) * 256;
    for (int e = (blockIdx.x >> 3) * 256 + threadIdx.x; e < E; e += stride) {
        int d = ei[E + e];
        if (d >= lo && d < hi) {
            int pos = atomicAdd(&cursor[d], 1);
            adj[pos] = ei[e];
        }
    }
}

// ---------------------------------------------------------------------------
// Pack BN-folded weights into MFMA B-fragment order, split bf16 hi/lo.
// 64 blocks: blk>>4 = layer (0..2) or head (3); blk&15 = chunk of the array.
// frag value: B[k = kk*32 + (lane>>4)*8 + j][n = ct*16 + (lane&15)]
// ---------------------------------------------------------------------------
__global__ void pack_kernel(const float* __restrict__ W1, const float* __restrict__ b1,
                            const float* __restrict__ g1, const float* __restrict__ bt1,
                            const float* __restrict__ m1, const float* __restrict__ v1,
                            const float* __restrict__ W2, const float* __restrict__ b2,
                            const float* __restrict__ gc, const float* __restrict__ bc,
                            const float* __restrict__ mc, const float* __restrict__ vc,
                            const float* __restrict__ l1W, const float* __restrict__ l1b,
                            const float* __restrict__ gbn, const float* __restrict__ bbn,
                            const float* __restrict__ mbn, const float* __restrict__ vbn,
                            const float* __restrict__ l2W, const float* __restrict__ l2b,
                            unsigned short* __restrict__ w1p, unsigned short* __restrict__ w2p,
                            float* __restrict__ bias1, float* __restrict__ bias2,
                            unsigned short* __restrict__ w1ph, unsigned short* __restrict__ w2ph,
                            float* __restrict__ bias1h, float* __restrict__ bias2h) {
    int l = blockIdx.x >> 4, chunk = blockIdx.x & 15, t = threadIdx.x;
    if (l < 3) {
        const float* W1l = W1 + (size_t)l * 64 * 128;
        const float* W2l = W2 + (size_t)l * 128 * 64;
        if (chunk == 0) {
            if (t < 128) {
                float s = g1[l * 128 + t] * rsqrtf(v1[l * 128 + t] + BN_EPS);
                bias1[l * 128 + t] = (b1[l * 128 + t] - m1[l * 128 + t]) * s + bt1[l * 128 + t];
            }
            if (t < 64) {
                float s = gc[l * 64 + t] * rsqrtf(vc[l * 64 + t] + BN_EPS);
                bias2[l * 64 + t] = (b2[l * 64 + t] - mc[l * 64 + t]) * s + bc[l * 64 + t];
            }
        }
        for (int idx = chunk * 1024 + t; idx < chunk * 1024 + 1024; idx += 256) {
            int j = idx & 7, lane = (idx >> 3) & 63, hl = (idx >> 9) & 1;
            int kk = (idx >> 10) & 1, ct = idx >> 11;
            int k = kk * 32 + (lane >> 4) * 8 + j;
            int nn = ct * 16 + (lane & 15);
            float s = g1[l * 128 + nn] * rsqrtf(v1[l * 128 + nn] + BN_EPS);
            float w = W1l[k * 128 + nn] * s;
            unsigned short hi = f2bf(w);
            w1p[(size_t)l * 16384 + idx] = hl ? f2bf(w - bf2f(hi)) : hi;
        }
        for (int idx = chunk * 1024 + t; idx < chunk * 1024 + 1024; idx += 256) {
            int j = idx & 7, lane = (idx >> 3) & 63, hl = (idx >> 9) & 1;
            int kk = (idx >> 10) & 3, ct = idx >> 12;
            int k = kk * 32 + (lane >> 4) * 8 + j;
            int nn = ct * 16 + (lane & 15);
            float s = gc[l * 64 + nn] * rsqrtf(vc[l * 64 + nn] + BN_EPS);
            float w = W2l[k * 64 + nn] * s;
            unsigned short hi = f2bf(w);
            w2p[(size_t)l * 16384 + idx] = hl ? f2bf(w - bf2f(hi)) : hi;
        }
    } else {
        // head: lin1 (64x64, BN-folded) and lin2 (64x40 zero-padded to 64)
        if (chunk == 0 && t < 64) {
            float s = gbn[t] * rsqrtf(vbn[t] + BN_EPS);
            bias1h[t] = (l1b[t] - mbn[t]) * s + bbn[t];
            bias2h[t] = (t < 40) ? l2b[t] : 0.0f;
        }
        for (int idx = chunk * 512 + t; idx < chunk * 512 + 512; idx += 256) {
            int j = idx & 7, lane = (idx >> 3) & 63, hl = (idx >> 9) & 1;
            int kk = (idx >> 10) & 1, ct = idx >> 11;   // ct<4
            int k = kk * 32 + (lane >> 4) * 8 + j;
            int nn = ct * 16 + (lane & 15);
            float s = gbn[nn] * rsqrtf(vbn[nn] + BN_EPS);
            float w = l1W[k * 64 + nn] * s;
            unsigned short hi = f2bf(w);
            w1ph[idx] = hl ? f2bf(w - bf2f(hi)) : hi;
        }
        for (int idx = chunk * 512 + t; idx < chunk * 512 + 512; idx += 256) {
            int j = idx & 7, lane = (idx >> 3) & 63, hl = (idx >> 9) & 1;
            int kk = (idx >> 10) & 1, ct = idx >> 11;
            int k = kk * 32 + (lane >> 4) * 8 + j;
            int nn = ct * 16 + (lane & 15);
            float w = (nn < 40) ? l2W[k * 40 + nn] : 0.0f;
            unsigned short hi = f2bf(w);
            w2ph[idx] = hl ? f2bf(w - bf2f(hi)) : hi;
        }
    }
}

// ---------------------------------------------------------------------------
// h[i] = x[i] + sum_{j in N(i)} x[j]; TWO nodes per wave (32 lanes x float2
// each = 256B/row coalescing), 4 load chains per half-wave -> 8 outstanding
// loads/wave (2x MLP vs 1 node/wave). Emits bf16 hi/lo for the MFMA A-op.
// ---------------------------------------------------------------------------
__global__ void gather_kernel(const float* __restrict__ x, const int* __restrict__ adj,
                              const int* __restrict__ offs, const int* __restrict__ deg,
                              unsigned short* __restrict__ hhi,
                              unsigned short* __restrict__ hlo, int n) {
    int gid = blockIdx.x * blockDim.x + threadIdx.x;
    int wave = gid >> 6;
    int lane = threadIdx.x & 63;
    int half = lane >> 5, sub = lane & 31;
    int node = wave * 2 + half;
    if (node >= n) return;          // halves are shfl-independent; safe
    int d = deg[node];
    int off = offs[node];
    const float2* x2 = (const float2*)x;
    float2 acc = x2[(size_t)node * 32 + sub];   // self term (GIN eps=0)
    float2 a1 = {0.f, 0.f}, a2 = {0.f, 0.f}, a3 = {0.f, 0.f};
    int sbase = half * 32;
    for (int base = 0; base < d; base += 32) {
        int m = d - base; if (m > 32) m = 32;
        int myslot = (sub < m) ? adj[off + base + sub] : 0;
        int c = 0;
        for (; c + 4 <= m; c += 4) {
            int s0 = __shfl(myslot, sbase + c, 64);
            int s1 = __shfl(myslot, sbase + c + 1, 64);
            int s2 = __shfl(myslot, sbase + c + 2, 64);
            int s3 = __shfl(myslot, sbase + c + 3, 64);
            float2 v0 = x2[(size_t)s0 * 32 + sub];
            float2 v1 = x2[(size_t)s1 * 32 + sub];
            float2 v2 = x2[(size_t)s2 * 32 + sub];
            float2 v3 = x2[(size_t)s3 * 32 + sub];
            acc.x += v0.x; acc.y += v0.y;
            a1.x += v1.x;  a1.y += v1.y;
            a2.x += v2.x;  a2.y += v2.y;
            a3.x += v3.x;  a3.y += v3.y;
        }
        for (; c < m; ++c) {
            int s = __shfl(myslot, sbase + c, 64);
            float2 v = x2[(size_t)s * 32 + sub];
            acc.x += v.x; acc.y += v.y;
        }
    }
    acc.x += (a1.x + a2.x) + a3.x;
    acc.y += (a1.y + a2.y) + a3.y;
    unsigned short hx = f2bf(acc.x), hy = f2bf(acc.y);
    ushort2 hiv; hiv.x = hx; hiv.y = hy;
    ushort2 lov; lov.x = f2bf(acc.x - bf2f(hx)); lov.y = f2bf(acc.y - bf2f(hy));
    *(ushort2*)&hhi[(size_t)node * 64 + sub * 2] = hiv;
    *(ushort2*)&hlo[(size_t)node * 64 + sub * 2] = lov;
}

// ---------------------------------------------------------------------------
// MFMA GIN MLP, split-bf16 (hi+lo, 3 products) == fp32-accurate.
// Block = 4 waves, one 16-node tile. Wave w owns stage-A col-tiles {2w,2w+1}
// and stage-B col-tile w. Weights live in registers (pre-packed frags).
// ---------------------------------------------------------------------------
__global__ __launch_bounds__(256)
void mlp_mfma(const unsigned short* __restrict__ hhi, const unsigned short* __restrict__ hlo,
              const unsigned short* __restrict__ w1p, const unsigned short* __restrict__ w2p,
              const float* __restrict__ bias1, const float* __restrict__ bias2,
              float* __restrict__ xout, int n) {
    __shared__ __attribute__((aligned(16))) unsigned short h2hi[16 * 136];
    __shared__ __attribute__((aligned(16))) unsigned short h2lo[16 * 136];

    const int t = threadIdx.x;
    const int wv = t >> 6, lane = t & 63;
    const int quad = lane >> 4, l16 = lane & 15;

    short8 w1f[2][2][2];   // [ct_local][kk][hi/lo]
#pragma unroll
    for (int c = 0; c < 2; ++c)
#pragma unroll
        for (int kk = 0; kk < 2; ++kk)
#pragma unroll
            for (int hl = 0; hl < 2; ++hl) {
                int ct = wv * 2 + c;
                w1f[c][kk][hl] = *(const short8*)&w1p[(size_t)(((ct * 2 + kk) * 2 + hl) * 64 + lane) * 8];
            }
    short8 w2f[4][2];      // [kk][hi/lo], ct = wv
#pragma unroll
    for (int kk = 0; kk < 4; ++kk)
#pragma unroll
        for (int hl = 0; hl < 2; ++hl)
            w2f[kk][hl] = *(const short8*)&w2p[(size_t)(((wv * 4 + kk) * 2 + hl) * 64 + lane) * 8];

    float b1v0 = bias1[(wv * 2 + 0) * 16 + l16];
    float b1v1 = bias1[(wv * 2 + 1) * 16 + l16];
    float b2v  = bias2[wv * 16 + l16];

    const int tile = blockIdx.x * 16;
    int arow = tile + l16;
    if (arow >= n) arow = n - 1;

    const unsigned short* hr = hhi + (size_t)arow * 64 + quad * 8;
    const unsigned short* lr = hlo + (size_t)arow * 64 + quad * 8;
    short8 ah0 = *(const short8*)hr;
    short8 ah1 = *(const short8*)(hr + 32);
    short8 al0 = *(const short8*)lr;
    short8 al1 = *(const short8*)(lr + 32);

    floatx4 accA0 = {0.f, 0.f, 0.f, 0.f};
    floatx4 accA1 = {0.f, 0.f, 0.f, 0.f};
    accA0 = MFMA16(ah0, w1f[0][0][0], accA0);
    accA0 = MFMA16(ah0, w1f[0][0][1], accA0);
    accA0 = MFMA16(al0, w1f[0][0][0], accA0);
    accA0 = MFMA16(ah1, w1f[0][1][0], accA0);
    accA0 = MFMA16(ah1, w1f[0][1][1], accA0);
    accA0 = MFMA16(al1, w1f[0][1][0], accA0);
    accA1 = MFMA16(ah0, w1f[1][0][0], accA1);
    accA1 = MFMA16(ah0, w1f[1][0][1], accA1);
    accA1 = MFMA16(al0, w1f[1][0][0], accA1);
    accA1 = MFMA16(ah1, w1f[1][1][0], accA1);
    accA1 = MFMA16(ah1, w1f[1][1][1], accA1);
    accA1 = MFMA16(al1, w1f[1][1][0], accA1);

#pragma unroll
    for (int r = 0; r < 4; ++r) {
        int node = quad * 4 + r;
        {
            float v = fmaxf(accA0[r] + b1v0, 0.f);
            unsigned short hi = f2bf(v);
            int col = (wv * 2 + 0) * 16 + l16;
            h2hi[node * 136 + col] = hi;
            h2lo[node * 136 + col] = f2bf(v - bf2f(hi));
        }
        {
            float v = fmaxf(accA1[r] + b1v1, 0.f);
            unsigned short hi = f2bf(v);
            int col = (wv * 2 + 1) * 16 + l16;
            h2hi[node * 136 + col] = hi;
            h2lo[node * 136 + col] = f2bf(v - bf2f(hi));
        }
    }
    __syncthreads();

    floatx4 accB = {0.f, 0.f, 0.f, 0.f};
#pragma unroll
    for (int kk = 0; kk < 4; ++kk) {
        short8 a2h = *(const short8*)&h2hi[l16 * 136 + kk * 32 + quad * 8];
        short8 a2l = *(const short8*)&h2lo[l16 * 136 + kk * 32 + quad * 8];
        accB = MFMA16(a2h, w2f[kk][0], accB);
        accB = MFMA16(a2h, w2f[kk][1], accB);
        accB = MFMA16(a2l, w2f[kk][0], accB);
    }
    int col2 = wv * 16 + l16;
#pragma unroll
    for (int r = 0; r < 4; ++r) {
        int node = tile + quad * 4 + r;
        if (node < n)
            xout[(size_t)node * 64 + col2] = fmaxf(accB[r] + b2v, 0.f);
    }
}

// ---------------------------------------------------------------------------
// MFMA head: relu(bn1(x@lin1+b)) @ lin2pad -> log_softmax(40).
// Block = 4 waves, one 16-node tile; wave w owns col-tile w for both stages.
// ---------------------------------------------------------------------------
__global__ __launch_bounds__(256)
void head_mfma(const float* __restrict__ xin,
               const unsigned short* __restrict__ w1ph, const unsigned short* __restrict__ w2ph,
               const float* __restrict__ bias1h, const float* __restrict__ bias2h,
               float* __restrict__ out, int n) {
    __shared__ __attribute__((aligned(16))) unsigned short h2hi[16 * 72];
    __shared__ __attribute__((aligned(16))) unsigned short h2lo[16 * 72];
    __shared__ float zbuf[16][68];

    const int t = threadIdx.x;
    const int wv = t >> 6, lane = t & 63;
    const int quad = lane >> 4, l16 = lane & 15;

    short8 w1f[2][2];  // [kk][hi/lo], ct = wv
    short8 w2f[2][2];
#pragma unroll
    for (int kk = 0; kk < 2; ++kk)
#pragma unroll
        for (int hl = 0; hl < 2; ++hl) {
            w1f[kk][hl] = *(const short8*)&w1ph[(size_t)(((wv * 2 + kk) * 2 + hl) * 64 + lane) * 8];
            w2f[kk][hl] = *(const short8*)&w2ph[(size_t)(((wv * 2 + kk) * 2 + hl) * 64 + lane) * 8];
        }
    float b1v = bias1h[wv * 16 + l16];
    float b2v = bias2h[wv * 16 + l16];

    const int tile = blockIdx.x * 16;
    int arow = tile + l16;
    if (arow >= n) arow = n - 1;

    // A-frags from fp32 input, split hi/lo
    short8 ah[2], al[2];
#pragma unroll
    for (int kk = 0; kk < 2; ++kk) {
        const float* xr = xin + (size_t)arow * 64 + kk * 32 + quad * 8;
        float4 xa = *(const float4*)xr;
        float4 xb = *(const float4*)(xr + 4);
        float v[8] = {xa.x, xa.y, xa.z, xa.w, xb.x, xb.y, xb.z, xb.w};
#pragma unroll
        for (int j = 0; j < 8; ++j) {
            unsigned short hi = f2bf(v[j]);
            ah[kk][j] = (short)hi;
            al[kk][j] = (short)f2bf(v[j] - bf2f(hi));
        }
    }

    floatx4 accA = {0.f, 0.f, 0.f, 0.f};
#pragma unroll
    for (int kk = 0; kk < 2; ++kk) {
        accA = MFMA16(ah[kk], w1f[kk][0], accA);
        accA = MFMA16(ah[kk], w1f[kk][1], accA);
        accA = MFMA16(al[kk], w1f[kk][0], accA);
    }
#pragma unroll
    for (int r = 0; r < 4; ++r) {
        int node = quad * 4 + r;
        float v = fmaxf(accA[r] + b1v, 0.f);
        unsigned short hi = f2bf(v);
        int col = wv * 16 + l16;
        h2hi[node * 72 + col] = hi;
        h2lo[node * 72 + col] = f2bf(v - bf2f(hi));
    }
    __syncthreads();

    floatx4 accB = {0.f, 0.f, 0.f, 0.f};
#pragma unroll
    for (int kk = 0; kk < 2; ++kk) {
        short8 a2h = *(const short8*)&h2hi[l16 * 72 + kk * 32 + quad * 8];
        short8 a2l = *(const short8*)&h2lo[l16 * 72 + kk * 32 + quad * 8];
        accB = MFMA16(a2h, w2f[kk][0], accB);
        accB = MFMA16(a2h, w2f[kk][1], accB);
        accB = MFMA16(a2l, w2f[kk][0], accB);
    }
#pragma unroll
    for (int r = 0; r < 4; ++r)
        zbuf[quad * 4 + r][wv * 16 + l16] = accB[r] + b2v;
    __syncthreads();

    // log-softmax: wave wv handles nodes wv*4 .. wv*4+3; lanes 0..39 = classes
#pragma unroll
    for (int r = 0; r < 4; ++r) {
        int nl = wv * 4 + r;
        float zi = (lane < 40) ? zbuf[nl][lane] : -INFINITY;
        float mx = zi;
#pragma unroll
        for (int msk = 1; msk < 64; msk <<= 1)
            mx = fmaxf(mx, __shfl_xor(mx, msk, 64));
        float e = (lane < 40) ? __expf(zi - mx) : 0.f;
        float se = e;
#pragma unroll
        for (int msk = 1; msk < 64; msk <<= 1)
            se += __shfl_xor(se, msk, 64);
        float lse = mx + __logf(se);
        int node = tile + nl;
        if (lane < 40 && node < n)
            out[(size_t)node * 40 + lane] = zi - lse;
    }
}

// ---------------------------------------------------------------------------
extern "C" void kernel_launch(void* const* d_in, const int* in_sizes, int n_in,
                              void* d_out, int out_size, void* d_ws, size_t ws_size,
                              hipStream_t stream) {
    const float* x    = (const float*)d_in[0];
    const int*   ei   = (const int*)d_in[1];
    const float* W1   = (const float*)d_in[2];
    const float* b1   = (const float*)d_in[3];
    const float* g1   = (const float*)d_in[4];
    const float* bt1  = (const float*)d_in[5];
    const float* m1   = (const float*)d_in[6];
    const float* v1   = (const float*)d_in[7];
    const float* W2   = (const float*)d_in[8];
    const float* b2   = (const float*)d_in[9];
    const float* gc   = (const float*)d_in[10];
    const float* bc   = (const float*)d_in[11];
    const float* mc   = (const float*)d_in[12];
    const float* vc   = (const float*)d_in[13];
    const float* l1W  = (const float*)d_in[14];
    const float* l1b  = (const float*)d_in[15];
    const float* gbn  = (const float*)d_in[16];
    const float* bbn  = (const float*)d_in[17];
    const float* mbn  = (const float*)d_in[18];
    const float* vbn  = (const float*)d_in[19];
    const float* l2W  = (const float*)d_in[20];
    const float* l2b  = (const float*)d_in[21];
    float* out = (float*)d_out;

    int N = in_sizes[0] / 64;
    int E = in_sizes[1] / 2;

    char* w = (char*)d_ws;
    int* deg = (int*)w;              w += ((size_t)N * 4 + 255) / 256 * 256;
    int* offs = (int*)w;             w += ((size_t)N * 4 + 255) / 256 * 256;
    int* cursor = (int*)w;           w += ((size_t)N * 4 + 255) / 256 * 256;
    int* counter = (int*)w;          w += 256;
    int* adj = (int*)w;              w += ((size_t)E * 4 + 255) / 256 * 256;
    unsigned short* hhi = (unsigned short*)w;  w += (size_t)N * 64 * 2;
    unsigned short* hlo = (unsigned short*)w;  w += (size_t)N * 64 * 2;
    float* xb0 = (float*)w;          w += (size_t)N * 64 * 4;
    unsigned short* w1p = (unsigned short*)w;  w += 3 * 16384 * 2;
    unsigned short* w2p = (unsigned short*)w;  w += 3 * 16384 * 2;
    float* bias1 = (float*)w;        w += 3 * 128 * 4;
    float* bias2 = (float*)w;        w += 3 * 64 * 4;
    unsigned short* w1ph = (unsigned short*)w; w += 8192 * 2;
    unsigned short* w2ph = (unsigned short*)w; w += 8192 * 2;
    float* bias1h = (float*)w;       w += 64 * 4;
    float* bias2h = (float*)w;       w += 64 * 4;

    hipMemsetAsync(deg, 0, (size_t)N * 4, stream);
    hipMemsetAsync(counter, 0, 256, stream);
    // 8 partitions x 256 chunks = 2048 blocks
    hist_kernel<<<2048, 256, 0, stream>>>(ei, deg, E, N);
    alloc_kernel<<<(N + 255) / 256, 256, 0, stream>>>(deg, offs, cursor, counter, N);
    scatter_kernel<<<2048, 256, 0, stream>>>(ei, cursor, adj, E, N);
    pack_kernel<<<64, 256, 0, stream>>>(W1, b1, g1, bt1, m1, v1, W2, b2, gc, bc, mc, vc,
                                        l1W, l1b, gbn, bbn, mbn, vbn, l2W, l2b,
                                        w1p, w2p, bias1, bias2, w1ph, w2ph, bias1h, bias2h);

    const float* cur = x;
    int nblk = (N + 15) / 16;
    int gather_blocks = ((int)(((long long)N + 1) / 2) * 64 + 255) / 256;
    for (int l = 0; l < 3; ++l) {
        gather_kernel<<<gather_blocks, 256, 0, stream>>>(cur, adj, offs, deg, hhi, hlo, N);
        mlp_mfma<<<nblk, 256, 0, stream>>>(hhi, hlo,
                                           w1p + (size_t)l * 16384, w2p + (size_t)l * 16384,
                                           bias1 + (size_t)l * 128, bias2 + (size_t)l * 64,
                                           xb0, N);
        cur = xb0;
    }
    head_mfma<<<nblk, 256, 0, stream>>>(xb0, w1ph, w2ph, bias1h, bias2h, out, N);
}

// Round 7
// 319.737 us; speedup vs baseline: 1.5670x; 1.0941x over previous
//
#include <hip/hip_runtime.h>
#include <hip/hip_fp16.h>
#include <math.h>

#define BN_EPS 1e-5f

typedef _Float16 half8 __attribute__((ext_vector_type(8)));
typedef float floatx4 __attribute__((ext_vector_type(4)));

#define MFMA16H(a, b, c) __builtin_amdgcn_mfma_f32_16x16x32_f16((a), (b), (c), 0, 0, 0)

__device__ __forceinline__ unsigned short f2h(float x) {
    return __half_as_ushort(__float2half(x));
}
__device__ __forceinline__ float h2f(unsigned short b) {
    return __half2float(__ushort_as_half(b));
}

// ---------------------------------------------------------------------------
// CSR build, pass 1: degree histogram, XCD-partitioned by dst range.
// ---------------------------------------------------------------------------
__global__ void hist_kernel(const int* __restrict__ ei, int* __restrict__ deg,
                            int E, int n) {
    int part = blockIdx.x & 7;
    int lo = (int)((long long)part * n >> 3);
    int hi = (int)((long long)(part + 1) * n >> 3);
    int stride = (gridDim.x >> 3) * 256;
    for (int e = (blockIdx.x >> 3) * 256 + threadIdx.x; e < E; e += stride) {
        int d = ei[E + e];
        if (d >= lo && d < hi) atomicAdd(&deg[d], 1);
    }
}

// ---------------------------------------------------------------------------
// CSR build, pass 2: range allocation (wave prefix + one atomic per wave)
// ---------------------------------------------------------------------------
__global__ void alloc_kernel(const int* __restrict__ deg, int* __restrict__ offs,
                             int* __restrict__ cursor, int* __restrict__ counter, int n) {
    int i = blockIdx.x * 256 + threadIdx.x;
    int lane = threadIdx.x & 63;
    int d = (i < n) ? deg[i] : 0;
    int pre = d;
#pragma unroll
    for (int delta = 1; delta < 64; delta <<= 1) {
        int v = __shfl_up(pre, delta, 64);
        if (lane >= delta) pre += v;
    }
    int total = __shfl(pre, 63, 64);
    int excl = pre - d;
    int base = 0;
    if (lane == 0) base = atomicAdd(counter, total);
    base = __shfl(base, 0, 64);
    if (i < n) {
        offs[i] = base + excl;
        cursor[i] = base + excl;
    }
}

// ---------------------------------------------------------------------------
// CSR build, pass 3: scatter, XCD-partitioned by dst range
// ---------------------------------------------------------------------------
__global__ void scatter_kernel(const int* __restrict__ ei, int* __restrict__ cursor,
                               int* __restrict__ adj, int E, int n) {
    int part = blockIdx.x & 7;
    int lo = (int)((long long)part * n >> 3);
    int hi = (int)((long long)(part + 1) * n >> 3);
    int stride = (gridDim.x >> 3) * 256;
    for (int e = (blockIdx.x >> 3) * 256 + threadIdx.x; e < E; e += stride) {
        int d = ei[E + e];
        if (d >= lo && d < hi) {
            int pos = atomicAdd(&cursor[d], 1);
            adj[pos] = ei[e];
        }
    }
}

// ---------------------------------------------------------------------------
// Convert fp32 input x -> fp16 (one-time, 3 us)
// ---------------------------------------------------------------------------
__global__ void x2h_kernel(const float* __restrict__ x, unsigned short* __restrict__ xh,
                           int total4) {
    int i = blockIdx.x * 256 + threadIdx.x;
    if (i >= total4) return;
    float4 v = ((const float4*)x)[i];
    ushort4 o;
    o.x = f2h(v.x); o.y = f2h(v.y); o.z = f2h(v.z); o.w = f2h(v.w);
    ((ushort4*)xh)[i] = o;
}

// ---------------------------------------------------------------------------
// Pack BN-folded weights into MFMA B-fragment order, split fp16 hi/lo.
// 64 blocks: blk>>4 = layer (0..2) or head (3); blk&15 = chunk.
// frag value: B[k = kk*32 + (lane>>4)*8 + j][n = ct*16 + (lane&15)]
// ---------------------------------------------------------------------------
__global__ void pack_kernel(const float* __restrict__ W1, const float* __restrict__ b1,
                            const float* __restrict__ g1, const float* __restrict__ bt1,
                            const float* __restrict__ m1, const float* __restrict__ v1,
                            const float* __restrict__ W2, const float* __restrict__ b2,
                            const float* __restrict__ gc, const float* __restrict__ bc,
                            const float* __restrict__ mc, const float* __restrict__ vc,
                            const float* __restrict__ l1W, const float* __restrict__ l1b,
                            const float* __restrict__ gbn, const float* __restrict__ bbn,
                            const float* __restrict__ mbn, const float* __restrict__ vbn,
                            const float* __restrict__ l2W, const float* __restrict__ l2b,
                            unsigned short* __restrict__ w1p, unsigned short* __restrict__ w2p,
                            float* __restrict__ bias1, float* __restrict__ bias2,
                            unsigned short* __restrict__ w1ph, unsigned short* __restrict__ w2ph,
                            float* __restrict__ bias1h, float* __restrict__ bias2h) {
    int l = blockIdx.x >> 4, chunk = blockIdx.x & 15, t = threadIdx.x;
    if (l < 3) {
        const float* W1l = W1 + (size_t)l * 64 * 128;
        const float* W2l = W2 + (size_t)l * 128 * 64;
        if (chunk == 0) {
            if (t < 128) {
                float s = g1[l * 128 + t] * rsqrtf(v1[l * 128 + t] + BN_EPS);
                bias1[l * 128 + t] = (b1[l * 128 + t] - m1[l * 128 + t]) * s + bt1[l * 128 + t];
            }
            if (t < 64) {
                float s = gc[l * 64 + t] * rsqrtf(vc[l * 64 + t] + BN_EPS);
                bias2[l * 64 + t] = (b2[l * 64 + t] - mc[l * 64 + t]) * s + bc[l * 64 + t];
            }
        }
        for (int idx = chunk * 1024 + t; idx < chunk * 1024 + 1024; idx += 256) {
            int j = idx & 7, lane = (idx >> 3) & 63, hl = (idx >> 9) & 1;
            int kk = (idx >> 10) & 1, ct = idx >> 11;
            int k = kk * 32 + (lane >> 4) * 8 + j;
            int nn = ct * 16 + (lane & 15);
            float s = g1[l * 128 + nn] * rsqrtf(v1[l * 128 + nn] + BN_EPS);
            float w = W1l[k * 128 + nn] * s;
            unsigned short hi = f2h(w);
            w1p[(size_t)l * 16384 + idx] = hl ? f2h(w - h2f(hi)) : hi;
        }
        for (int idx = chunk * 1024 + t; idx < chunk * 1024 + 1024; idx += 256) {
            int j = idx & 7, lane = (idx >> 3) & 63, hl = (idx >> 9) & 1;
            int kk = (idx >> 10) & 3, ct = idx >> 12;
            int k = kk * 32 + (lane >> 4) * 8 + j;
            int nn = ct * 16 + (lane & 15);
            float s = gc[l * 64 + nn] * rsqrtf(vc[l * 64 + nn] + BN_EPS);
            float w = W2l[k * 64 + nn] * s;
            unsigned short hi = f2h(w);
            w2p[(size_t)l * 16384 + idx] = hl ? f2h(w - h2f(hi)) : hi;
        }
    } else {
        if (chunk == 0 && t < 64) {
            float s = gbn[t] * rsqrtf(vbn[t] + BN_EPS);
            bias1h[t] = (l1b[t] - mbn[t]) * s + bbn[t];
            bias2h[t] = (t < 40) ? l2b[t] : 0.0f;
        }
        for (int idx = chunk * 512 + t; idx < chunk * 512 + 512; idx += 256) {
            int j = idx & 7, lane = (idx >> 3) & 63, hl = (idx >> 9) & 1;
            int kk = (idx >> 10) & 1, ct = idx >> 11;
            int k = kk * 32 + (lane >> 4) * 8 + j;
            int nn = ct * 16 + (lane & 15);
            float s = gbn[nn] * rsqrtf(vbn[nn] + BN_EPS);
            float w = l1W[k * 64 + nn] * s;
            unsigned short hi = f2h(w);
            w1ph[idx] = hl ? f2h(w - h2f(hi)) : hi;
        }
        for (int idx = chunk * 512 + t; idx < chunk * 512 + 512; idx += 256) {
            int j = idx & 7, lane = (idx >> 3) & 63, hl = (idx >> 9) & 1;
            int kk = (idx >> 10) & 1, ct = idx >> 11;
            int k = kk * 32 + (lane >> 4) * 8 + j;
            int nn = ct * 16 + (lane & 15);
            float w = (nn < 40) ? l2W[k * 40 + nn] : 0.0f;
            unsigned short hi = f2h(w);
            w2ph[idx] = hl ? f2h(w - h2f(hi)) : hi;
        }
    }
}

// ---------------------------------------------------------------------------
// h[i] = x[i] + sum_j x[j], x in fp16 (128 B/row — half the R6 traffic).
// Two nodes per wave: 32 lanes x half2 per node. fp32 accumulate; emits
// fp16 hi/lo split of h for the f16-MFMA A-operand.
// ---------------------------------------------------------------------------
__global__ void gather_kernel(const __half2* __restrict__ xh2, const int* __restrict__ adj,
                              const int* __restrict__ offs, const int* __restrict__ deg,
                              unsigned short* __restrict__ hhi,
                              unsigned short* __restrict__ hlo, int n) {
    int gid = blockIdx.x * blockDim.x + threadIdx.x;
    int wave = gid >> 6;
    int lane = threadIdx.x & 63;
    int half = lane >> 5, sub = lane & 31;
    int node = wave * 2 + half;
    if (node >= n) return;
    int d = deg[node];
    int off = offs[node];
    float2 acc = __half22float2(xh2[(size_t)node * 32 + sub]);  // self (eps=0)
    float2 a1 = {0.f, 0.f}, a2 = {0.f, 0.f}, a3 = {0.f, 0.f};
    int sbase = half * 32;
    for (int base = 0; base < d; base += 32) {
        int m = d - base; if (m > 32) m = 32;
        int myslot = (sub < m) ? adj[off + base + sub] : 0;
        int c = 0;
        for (; c + 4 <= m; c += 4) {
            int s0 = __shfl(myslot, sbase + c, 64);
            int s1 = __shfl(myslot, sbase + c + 1, 64);
            int s2 = __shfl(myslot, sbase + c + 2, 64);
            int s3 = __shfl(myslot, sbase + c + 3, 64);
            float2 v0 = __half22float2(xh2[(size_t)s0 * 32 + sub]);
            float2 v1 = __half22float2(xh2[(size_t)s1 * 32 + sub]);
            float2 v2 = __half22float2(xh2[(size_t)s2 * 32 + sub]);
            float2 v3 = __half22float2(xh2[(size_t)s3 * 32 + sub]);
            acc.x += v0.x; acc.y += v0.y;
            a1.x += v1.x;  a1.y += v1.y;
            a2.x += v2.x;  a2.y += v2.y;
            a3.x += v3.x;  a3.y += v3.y;
        }
        for (; c < m; ++c) {
            int s = __shfl(myslot, sbase + c, 64);
            float2 v = __half22float2(xh2[(size_t)s * 32 + sub]);
            acc.x += v.x; acc.y += v.y;
        }
    }
    acc.x += (a1.x + a2.x) + a3.x;
    acc.y += (a1.y + a2.y) + a3.y;
    unsigned short hx = f2h(acc.x), hy = f2h(acc.y);
    ushort2 hiv; hiv.x = hx; hiv.y = hy;
    ushort2 lov; lov.x = f2h(acc.x - h2f(hx)); lov.y = f2h(acc.y - h2f(hy));
    *(ushort2*)&hhi[(size_t)node * 64 + sub * 2] = hiv;
    *(ushort2*)&hlo[(size_t)node * 64 + sub * 2] = lov;
}

// ---------------------------------------------------------------------------
// f16-MFMA GIN MLP, split hi/lo (3 products) ~= fp32-accurate (rel ~2^-22).
// Block = 4 waves, one 16-node tile. Output xh fp16 for next gather/head.
// ---------------------------------------------------------------------------
__global__ __launch_bounds__(256)
void mlp_mfma(const unsigned short* __restrict__ hhi, const unsigned short* __restrict__ hlo,
              const unsigned short* __restrict__ w1p, const unsigned short* __restrict__ w2p,
              const float* __restrict__ bias1, const float* __restrict__ bias2,
              unsigned short* __restrict__ xout, int n) {
    __shared__ __attribute__((aligned(16))) unsigned short h2hi[16 * 136];
    __shared__ __attribute__((aligned(16))) unsigned short h2lo[16 * 136];

    const int t = threadIdx.x;
    const int wv = t >> 6, lane = t & 63;
    const int quad = lane >> 4, l16 = lane & 15;

    half8 w1f[2][2][2];   // [ct_local][kk][hi/lo]
#pragma unroll
    for (int c = 0; c < 2; ++c)
#pragma unroll
        for (int kk = 0; kk < 2; ++kk)
#pragma unroll
            for (int hl = 0; hl < 2; ++hl) {
                int ct = wv * 2 + c;
                w1f[c][kk][hl] = *(const half8*)&w1p[(size_t)(((ct * 2 + kk) * 2 + hl) * 64 + lane) * 8];
            }
    half8 w2f[4][2];      // [kk][hi/lo], ct = wv
#pragma unroll
    for (int kk = 0; kk < 4; ++kk)
#pragma unroll
        for (int hl = 0; hl < 2; ++hl)
            w2f[kk][hl] = *(const half8*)&w2p[(size_t)(((wv * 4 + kk) * 2 + hl) * 64 + lane) * 8];

    float b1v0 = bias1[(wv * 2 + 0) * 16 + l16];
    float b1v1 = bias1[(wv * 2 + 1) * 16 + l16];
    float b2v  = bias2[wv * 16 + l16];

    const int tile = blockIdx.x * 16;
    int arow = tile + l16;
    if (arow >= n) arow = n - 1;

    const unsigned short* hr = hhi + (size_t)arow * 64 + quad * 8;
    const unsigned short* lr = hlo + (size_t)arow * 64 + quad * 8;
    half8 ah0 = *(const half8*)hr;
    half8 ah1 = *(const half8*)(hr + 32);
    half8 al0 = *(const half8*)lr;
    half8 al1 = *(const half8*)(lr + 32);

    floatx4 accA0 = {0.f, 0.f, 0.f, 0.f};
    floatx4 accA1 = {0.f, 0.f, 0.f, 0.f};
    accA0 = MFMA16H(ah0, w1f[0][0][0], accA0);
    accA0 = MFMA16H(ah0, w1f[0][0][1], accA0);
    accA0 = MFMA16H(al0, w1f[0][0][0], accA0);
    accA0 = MFMA16H(ah1, w1f[0][1][0], accA0);
    accA0 = MFMA16H(ah1, w1f[0][1][1], accA0);
    accA0 = MFMA16H(al1, w1f[0][1][0], accA0);
    accA1 = MFMA16H(ah0, w1f[1][0][0], accA1);
    accA1 = MFMA16H(ah0, w1f[1][0][1], accA1);
    accA1 = MFMA16H(al0, w1f[1][0][0], accA1);
    accA1 = MFMA16H(ah1, w1f[1][1][0], accA1);
    accA1 = MFMA16H(ah1, w1f[1][1][1], accA1);
    accA1 = MFMA16H(al1, w1f[1][1][0], accA1);

#pragma unroll
    for (int r = 0; r < 4; ++r) {
        int node = quad * 4 + r;
        {
            float v = fmaxf(accA0[r] + b1v0, 0.f);
            unsigned short hi = f2h(v);
            int col = (wv * 2 + 0) * 16 + l16;
            h2hi[node * 136 + col] = hi;
            h2lo[node * 136 + col] = f2h(v - h2f(hi));
        }
        {
            float v = fmaxf(accA1[r] + b1v1, 0.f);
            unsigned short hi = f2h(v);
            int col = (wv * 2 + 1) * 16 + l16;
            h2hi[node * 136 + col] = hi;
            h2lo[node * 136 + col] = f2h(v - h2f(hi));
        }
    }
    __syncthreads();

    floatx4 accB = {0.f, 0.f, 0.f, 0.f};
#pragma unroll
    for (int kk = 0; kk < 4; ++kk) {
        half8 a2h = *(const half8*)&h2hi[l16 * 136 + kk * 32 + quad * 8];
        half8 a2l = *(const half8*)&h2lo[l16 * 136 + kk * 32 + quad * 8];
        accB = MFMA16H(a2h, w2f[kk][0], accB);
        accB = MFMA16H(a2h, w2f[kk][1], accB);
        accB = MFMA16H(a2l, w2f[kk][0], accB);
    }
    int col2 = wv * 16 + l16;
#pragma unroll
    for (int r = 0; r < 4; ++r) {
        int node = tile + quad * 4 + r;
        if (node < n)
            xout[(size_t)node * 64 + col2] = f2h(fmaxf(accB[r] + b2v, 0.f));
    }
}

// ---------------------------------------------------------------------------
// f16-MFMA head: relu(bn1(x@lin1+b)) @ lin2pad -> log_softmax(40).
// A-operand is fp16 x directly (2 MFMAs per kk); stage B keeps hi/lo.
// ---------------------------------------------------------------------------
__global__ __launch_bounds__(256)
void head_mfma(const unsigned short* __restrict__ xin,
               const unsigned short* __restrict__ w1ph, const unsigned short* __restrict__ w2ph,
               const float* __restrict__ bias1h, const float* __restrict__ bias2h,
               float* __restrict__ out, int n) {
    __shared__ __attribute__((aligned(16))) unsigned short h2hi[16 * 72];
    __shared__ __attribute__((aligned(16))) unsigned short h2lo[16 * 72];
    __shared__ float zbuf[16][68];

    const int t = threadIdx.x;
    const int wv = t >> 6, lane = t & 63;
    const int quad = lane >> 4, l16 = lane & 15;

    half8 w1f[2][2];  // [kk][hi/lo], ct = wv
    half8 w2f[2][2];
#pragma unroll
    for (int kk = 0; kk < 2; ++kk)
#pragma unroll
        for (int hl = 0; hl < 2; ++hl) {
            w1f[kk][hl] = *(const half8*)&w1ph[(size_t)(((wv * 2 + kk) * 2 + hl) * 64 + lane) * 8];
            w2f[kk][hl] = *(const half8*)&w2ph[(size_t)(((wv * 2 + kk) * 2 + hl) * 64 + lane) * 8];
        }
    float b1v = bias1h[wv * 16 + l16];
    float b2v = bias2h[wv * 16 + l16];

    const int tile = blockIdx.x * 16;
    int arow = tile + l16;
    if (arow >= n) arow = n - 1;

    half8 ax[2];
#pragma unroll
    for (int kk = 0; kk < 2; ++kk)
        ax[kk] = *(const half8*)&xin[(size_t)arow * 64 + kk * 32 + quad * 8];

    floatx4 accA = {0.f, 0.f, 0.f, 0.f};
#pragma unroll
    for (int kk = 0; kk < 2; ++kk) {
        accA = MFMA16H(ax[kk], w1f[kk][0], accA);
        accA = MFMA16H(ax[kk], w1f[kk][1], accA);
    }
#pragma unroll
    for (int r = 0; r < 4; ++r) {
        int node = quad * 4 + r;
        float v = fmaxf(accA[r] + b1v, 0.f);
        unsigned short hi = f2h(v);
        int col = wv * 16 + l16;
        h2hi[node * 72 + col] = hi;
        h2lo[node * 72 + col] = f2h(v - h2f(hi));
    }
    __syncthreads();

    floatx4 accB = {0.f, 0.f, 0.f, 0.f};
#pragma unroll
    for (int kk = 0; kk < 2; ++kk) {
        half8 a2h = *(const half8*)&h2hi[l16 * 72 + kk * 32 + quad * 8];
        half8 a2l = *(const half8*)&h2lo[l16 * 72 + kk * 32 + quad * 8];
        accB = MFMA16H(a2h, w2f[kk][0], accB);
        accB = MFMA16H(a2h, w2f[kk][1], accB);
        accB = MFMA16H(a2l, w2f[kk][0], accB);
    }
#pragma unroll
    for (int r = 0; r < 4; ++r)
        zbuf[quad * 4 + r][wv * 16 + l16] = accB[r] + b2v;
    __syncthreads();

#pragma unroll
    for (int r = 0; r < 4; ++r) {
        int nl = wv * 4 + r;
        float zi = (lane < 40) ? zbuf[nl][lane] : -INFINITY;
        float mx = zi;
#pragma unroll
        for (int msk = 1; msk < 64; msk <<= 1)
            mx = fmaxf(mx, __shfl_xor(mx, msk, 64));
        float e = (lane < 40) ? __expf(zi - mx) : 0.f;
        float se = e;
#pragma unroll
        for (int msk = 1; msk < 64; msk <<= 1)
            se += __shfl_xor(se, msk, 64);
        float lse = mx + __logf(se);
        int node = tile + nl;
        if (lane < 40 && node < n)
            out[(size_t)node * 40 + lane] = zi - lse;
    }
}

// ---------------------------------------------------------------------------
extern "C" void kernel_launch(void* const* d_in, const int* in_sizes, int n_in,
                              void* d_out, int out_size, void* d_ws, size_t ws_size,
                              hipStream_t stream) {
    const float* x    = (const float*)d_in[0];
    const int*   ei   = (const int*)d_in[1];
    const float* W1   = (const float*)d_in[2];
    const float* b1   = (const float*)d_in[3];
    const float* g1   = (const float*)d_in[4];
    const float* bt1  = (const float*)d_in[5];
    const float* m1   = (const float*)d_in[6];
    const float* v1   = (const float*)d_in[7];
    const float* W2   = (const float*)d_in[8];
    const float* b2   = (const float*)d_in[9];
    const float* gc   = (const float*)d_in[10];
    const float* bc   = (const float*)d_in[11];
    const float* mc   = (const float*)d_in[12];
    const float* vc   = (const float*)d_in[13];
    const float* l1W  = (const float*)d_in[14];
    const float* l1b  = (const float*)d_in[15];
    const float* gbn  = (const float*)d_in[16];
    const float* bbn  = (const float*)d_in[17];
    const float* mbn  = (const float*)d_in[18];
    const float* vbn  = (const float*)d_in[19];
    const float* l2W  = (const float*)d_in[20];
    const float* l2b  = (const float*)d_in[21];
    float* out = (float*)d_out;

    int N = in_sizes[0] / 64;
    int E = in_sizes[1] / 2;

    char* w = (char*)d_ws;
    int* deg = (int*)w;              w += ((size_t)N * 4 + 255) / 256 * 256;
    int* offs = (int*)w;             w += ((size_t)N * 4 + 255) / 256 * 256;
    int* cursor = (int*)w;           w += ((size_t)N * 4 + 255) / 256 * 256;
    int* counter = (int*)w;          w += 256;
    int* adj = (int*)w;              w += ((size_t)E * 4 + 255) / 256 * 256;
    unsigned short* hhi = (unsigned short*)w;  w += (size_t)N * 64 * 2;
    unsigned short* hlo = (unsigned short*)w;  w += (size_t)N * 64 * 2;
    unsigned short* xh0 = (unsigned short*)w;  w += (size_t)N * 64 * 2;
    unsigned short* xh1 = (unsigned short*)w;  w += (size_t)N * 64 * 2;
    unsigned short* w1p = (unsigned short*)w;  w += 3 * 16384 * 2;
    unsigned short* w2p = (unsigned short*)w;  w += 3 * 16384 * 2;
    float* bias1 = (float*)w;        w += 3 * 128 * 4;
    float* bias2 = (float*)w;        w += 3 * 64 * 4;
    unsigned short* w1ph = (unsigned short*)w; w += 8192 * 2;
    unsigned short* w2ph = (unsigned short*)w; w += 8192 * 2;
    float* bias1h = (float*)w;       w += 64 * 4;
    float* bias2h = (float*)w;       w += 64 * 4;

    hipMemsetAsync(deg, 0, (size_t)N * 4, stream);
    hipMemsetAsync(counter, 0, 256, stream);
    hist_kernel<<<2048, 256, 0, stream>>>(ei, deg, E, N);
    alloc_kernel<<<(N + 255) / 256, 256, 0, stream>>>(deg, offs, cursor, counter, N);
    scatter_kernel<<<2048, 256, 0, stream>>>(ei, cursor, adj, E, N);
    pack_kernel<<<64, 256, 0, stream>>>(W1, b1, g1, bt1, m1, v1, W2, b2, gc, bc, mc, vc,
                                        l1W, l1b, gbn, bbn, mbn, vbn, l2W, l2b,
                                        w1p, w2p, bias1, bias2, w1ph, w2ph, bias1h, bias2h);
    x2h_kernel<<<(N * 16 + 255) / 256, 256, 0, stream>>>(x, xh0, N * 16);

    const unsigned short* cur = xh0;
    int nblk = (N + 15) / 16;
    int gather_blocks = ((int)(((long long)N + 1) / 2) * 64 + 255) / 256;
    for (int l = 0; l < 3; ++l) {
        gather_kernel<<<gather_blocks, 256, 0, stream>>>((const __half2*)cur, adj, offs, deg,
                                                         hhi, hlo, N);
        mlp_mfma<<<nblk, 256, 0, stream>>>(hhi, hlo,
                                           w1p + (size_t)l * 16384, w2p + (size_t)l * 16384,
                                           bias1 + (size_t)l * 128, bias2 + (size_t)l * 64,
                                           xh1, N);
        cur = xh1;
    }
    head_mfma<<<nblk, 256, 0, stream>>>(xh1, w1ph, w2ph, bias1h, bias2h, out, N);
}